// Round 14
// baseline (428.161 us; speedup 1.0000x reference)
//
#include <hip/hip_runtime.h>

// ---------------- problem constants ----------------
constexpr int ND_   = 12288;           // 3*B
constexpr int K_    = 10;
constexpr int NTOT  = ND_ * (1 + K_);  // 135168
constexpr int B_    = 4096;
constexpr int RKV   = ND_ * K_;        // 122880

// ---------------- ws layout (float offsets) ----------------
constexpr size_t OFF_QB   = 0;          // ushort[ND_*128]
constexpr size_t OFF_AGG  = 786432;     // ushort[ND_*128]
constexpr size_t OFF_HB   = 43253760;   // ushort[NTOT*128] -> 8,650,752 fl
constexpr size_t OFF_KVB  = 51904512;   // ushort[RKV*256]  -> 15,728,640 fl
constexpr size_t OFF_EMB  = 67633152;   // float[ND_*128]   -> 1,572,864
constexpr size_t OFF_WCAT = 69206016;   // ushort[640*512]  -> 163,840 fl
constexpr size_t OFF_WKV  = 69369856;   // ushort[384*256]  -> 49,152 fl
constexpr size_t OFF_BCAT = 69419008;   // float[512]
constexpr size_t OFF_BKV  = 69419520;   // float[256]
constexpr size_t OFF_WQB  = 69419776;   // ushort[128*128]
constexpr size_t OFF_WOB  = 69427968;   // ushort[256*128]
constexpr size_t OFF_SWP  = 69444352;   // float4[32*128]
constexpr size_t OFF_DWP  = 69460736;   // float4[32*128]
constexpr size_t OFF_QZ   = 69477120;   // float[128]

#define DEVFN __device__ __forceinline__

typedef __attribute__((ext_vector_type(8))) short bf16x8;
typedef __attribute__((ext_vector_type(4))) float f32x4;
#define MFMA16(a, b, c) __builtin_amdgcn_mfma_f32_16x16x32_bf16((a), (b), (c), 0, 0, 0)

DEVFN unsigned short f2bf(float x) {           // RNE float->bf16 (scalar path)
  unsigned int u = __float_as_uint(x);
  u = (u + 0x7FFFu + ((u >> 16) & 1u)) >> 16;
  return (unsigned short)u;
}
DEVFN float bf2f(unsigned short h) { return __uint_as_float(((unsigned int)h) << 16); }

// packed RNE f32->bf16 via HW cvt
DEVFN bf16x8 packcvt(float4 a, float4 b) {
  union { unsigned int u[4]; bf16x8 v; } r;
  asm("v_cvt_pk_bf16_f32 %0, %1, %2" : "=v"(r.u[0]) : "v"(a.x), "v"(a.y));
  asm("v_cvt_pk_bf16_f32 %0, %1, %2" : "=v"(r.u[1]) : "v"(a.z), "v"(a.w));
  asm("v_cvt_pk_bf16_f32 %0, %1, %2" : "=v"(r.u[2]) : "v"(b.x), "v"(b.y));
  asm("v_cvt_pk_bf16_f32 %0, %1, %2" : "=v"(r.u[3]) : "v"(b.z), "v"(b.w));
  return r.v;
}

DEVFN float dot4(const float4 a, const float4 b, float acc) {
  acc = fmaf(a.x, b.x, acc);
  acc = fmaf(a.y, b.y, acc);
  acc = fmaf(a.z, b.z, acc);
  acc = fmaf(a.w, b.w, acc);
  return acc;
}
// fast transcendentals (error ~1e-6 rel, << bf16 quantization)
DEVFN float fsig(float x)  { return __fdividef(1.0f, 1.0f + __expf(-x)); }
DEVFN float ftanh(float x) {
  x = fminf(fmaxf(x, -15.0f), 15.0f);
  const float t = __expf(2.0f * x);
  return __fdividef(t - 1.0f, t + 1.0f);
}

// ---------------- k0_all: all weight/bias packs in one launch ----------------
// Wcat c'-mapping: c' = q*128 + jb*64 + g*16 + t, channel j = q*32 + jb*16 + t, g in {R,Z,Ni,Nh}.
// k<512: w_ih (R/Z/Ni; zero Nh); k>=512: w_hh (R/Z/Nh; zero Ni).
__global__ void k0_all(const float* __restrict__ w_ih, const float* __restrict__ w_hh,
                       const float* __restrict__ wk,   const float* __restrict__ wv,
                       const float* __restrict__ wq,   const float* __restrict__ wo,
                       const float* __restrict__ sw,   const float* __restrict__ dwm,
                       const float* __restrict__ b_ih, const float* __restrict__ b_hh,
                       const float* __restrict__ bk,   const float* __restrict__ bv,
                       const float* __restrict__ time_b, const float* __restrict__ bq,
                       unsigned short* __restrict__ WcatP, unsigned short* __restrict__ WkvP,
                       unsigned short* __restrict__ WqB,   unsigned short* __restrict__ WoB,
                       float4* __restrict__ SwP, float4* __restrict__ DwP,
                       float* __restrict__ bcat, float* __restrict__ bkv,
                       float* __restrict__ qzero)
{
  int gid = blockIdx.x * 256 + threadIdx.x;
  if (gid < 327680) {                    // WcatP: 20 kt x 32 nt
    int f = gid >> 9, idx = gid & 511;
    int l = idx >> 3, j8 = idx & 7;
    int kt = f >> 5, nt = f & 31;
    int k = kt * 32 + (l >> 4) * 8 + j8;
    int c = nt * 16 + (l & 15);
    int q = c >> 7, jb = (c >> 6) & 1, g = (c >> 4) & 3, j = q * 32 + jb * 16 + (c & 15);
    float w;
    if (g == 0)      w = (k < 512) ? w_ih[(size_t)j * 512 + k]         : w_hh[(size_t)j * 128 + (k - 512)];
    else if (g == 1) w = (k < 512) ? w_ih[(size_t)(128 + j) * 512 + k] : w_hh[(size_t)(128 + j) * 128 + (k - 512)];
    else if (g == 2) w = (k < 512) ? w_ih[(size_t)(256 + j) * 512 + k] : 0.0f;
    else             w = (k < 512) ? 0.0f : w_hh[(size_t)(256 + j) * 128 + (k - 512)];
    WcatP[gid] = f2bf(w);
    return;
  }
  gid -= 327680;
  if (gid < 98304) {                     // WkvP: 12 kt x 16 nt (K|V)
    int f = gid >> 9, idx = gid & 511;
    int l = idx >> 3, j8 = idx & 7;
    int kt = f >> 4, nt = f & 15;
    int k = kt * 32 + (l >> 4) * 8 + j8;
    int c = nt * 16 + (l & 15);
    float w = (c < 128) ? wk[(size_t)c * 384 + k] : wv[(size_t)(c - 128) * 384 + k];
    WkvP[gid] = f2bf(w);
    return;
  }
  gid -= 98304;
  if (gid < 49152) {                     // WqB (4x8) then WoB (8x8)
    if (gid < 16384) {
      int f = gid >> 9, idx = gid & 511;
      int l = idx >> 3, j8 = idx & 7;
      int kt = f >> 3, nt = f & 7;
      int k = kt * 32 + (l >> 4) * 8 + j8;
      int c = nt * 16 + (l & 15);
      WqB[gid] = f2bf(wq[(size_t)c * 256 + k]);
    } else {
      int g2 = gid - 16384;
      int f = g2 >> 9, idx = g2 & 511;
      int l = idx >> 3, j8 = idx & 7;
      int kt = f >> 3, nt = f & 7;
      int k = kt * 32 + (l >> 4) * 8 + j8;
      int c = nt * 16 + (l & 15);
      WoB[g2] = f2bf(wo[(size_t)c * 256 + k]);
    }
    return;
  }
  gid -= 49152;
  if (gid < 8960) {                      // SwP / DwP / bcat / bkv
    if (gid < 4096) {
      int k4 = gid / 128, c = gid % 128;
      const float* s = sw + c * 128 + 4 * k4;
      SwP[gid] = make_float4(s[0], s[1], s[2], s[3]);
    } else if (gid < 8192) {
      int id = gid - 4096;
      int k4 = id / 128, c = id % 128;
      const float* s = dwm + c * 128 + 4 * k4;
      DwP[id] = make_float4(s[0], s[1], s[2], s[3]);
    } else if (gid < 8704) {
      int id = gid - 8192;
      int q = id >> 7, jb = (id >> 6) & 1, g = (id >> 4) & 3, lcc = id & 15;
      int j = q * 32 + jb * 16 + lcc;
      float b;
      if (g == 0)      b = b_ih[j] + b_hh[j];
      else if (g == 1) b = b_ih[128 + j] + b_hh[128 + j];
      else if (g == 2) b = b_ih[256 + j];
      else             b = b_hh[256 + j];
      bcat[id] = b;
    } else {
      int id = gid - 8704;
      bkv[id] = (id < 128) ? bk[id] : bv[id - 128];
    }
    return;
  }
  gid -= 8960;
  if (gid < 128) {                       // qzero (accurate cos, one-off)
    float acc = bq[gid];
    for (int k = 0; k < 128; ++k)
      acc = fmaf(cosf(time_b[k]), wq[gid * 256 + 128 + k], acc);
    qzero[gid] = acc;
  }
}

// ---------------- k1_fused: 64-row chunk-pipelined staged MFMA GRU ----------------
// Identical to R13 except __launch_bounds__(512,3): 170-reg cap fits the live set
// (64 AGPR acc + ~70 arch incl. tenc transients) -> removes the 120MB/launch scratch
// spill that sat inside the chunk loop (R13: WRITE_SIZE 154MB vs 34MB ideal).
__global__ __launch_bounds__(512, 3) void k1_fused(
    const int* __restrict__ nodes, const float* __restrict__ mail_data,
    const float* __restrict__ mem_data, const float* __restrict__ mail_time,
    const float* __restrict__ mem_time, const float* __restrict__ time_w,
    const float* __restrict__ time_b, const unsigned short* __restrict__ WcatP,
    const float* __restrict__ bcat, const float* __restrict__ nfeat,
    unsigned short* __restrict__ hb)
{
  __shared__ unsigned short As[2][2 * 2048];   // 2 bufs x (2 kt x 4KB)
  const int tid = threadIdx.x;
  const int rbase = blockIdx.x * 64;

  // stage mapping: thread t -> chunk-local kt (t>>8), slot (t&255); one 16B slot per chunk
  const int ktl  = tid >> 8;
  const int slot = tid & 255;
  const int smt = slot >> 6, sq = (slot >> 4) & 3, sr15 = slot & 15;
  const int srow = smt * 16 + sr15;
  const int sn = nodes[rbase + srow];
  const float sdrow = mail_time[sn] - mem_time[sn];
  const float* mailp = mail_data + (size_t)sn * 384;
  const float* memp  = mem_data  + (size_t)sn * 128;
  unsigned short* const ws0 = &As[0][(size_t)ktl * 2048 + (size_t)slot * 8];
  unsigned short* const ws1 = &As[1][(size_t)ktl * 2048 + (size_t)slot * 8];

  auto gather = [&](int kt, float4& v0, float4& v1) {
    const int c0 = kt * 32 + sq * 8;
    if (c0 < 384) {
      v0 = *(const float4*)(mailp + c0);
      v1 = *(const float4*)(mailp + c0 + 4);
    } else if (c0 >= 512) {
      v0 = *(const float4*)(memp + c0 - 512);
      v1 = *(const float4*)(memp + c0 - 508);
    } else {
      const float4 w0 = *(const float4*)(time_w + c0 - 384);
      const float4 w1 = *(const float4*)(time_w + c0 - 380);
      const float4 b0 = *(const float4*)(time_b + c0 - 384);
      const float4 b1 = *(const float4*)(time_b + c0 - 380);
      v0.x = __cosf(fmaf(sdrow, w0.x, b0.x)); v0.y = __cosf(fmaf(sdrow, w0.y, b0.y));
      v0.z = __cosf(fmaf(sdrow, w0.z, b0.z)); v0.w = __cosf(fmaf(sdrow, w0.w, b0.w));
      v1.x = __cosf(fmaf(sdrow, w1.x, b1.x)); v1.y = __cosf(fmaf(sdrow, w1.y, b1.y));
      v1.z = __cosf(fmaf(sdrow, w1.z, b1.z)); v1.w = __cosf(fmaf(sdrow, w1.w, b1.w));
    }
  };

  // ---- prologue: stage chunk 0 (kt 0,1) into buf 0 ----
  {
    float4 v0, v1;
    gather(ktl, v0, v1);
    *(bf16x8*)ws0 = packcvt(v0, v1);
  }
  __syncthreads();

  // ---- MFMA identities ----
  const int w = tid >> 6, l = tid & 63;
  const int lr = l >> 4, lc = l & 15;
  const unsigned short* Bp = WcatP + (size_t)(w * 4) * 512 + l * 8;

  f32x4 acc[4][4];
  #pragma unroll
  for (int m = 0; m < 4; ++m)
    #pragma unroll
    for (int bn = 0; bn < 4; ++bn) acc[m][bn] = (f32x4){0.f, 0.f, 0.f, 0.f};

  #pragma unroll
  for (int c = 0; c < 10; ++c) {
    float4 nv0, nv1;
    if (c < 9) gather((c + 1) * 2 + ktl, nv0, nv1);     // issue next-chunk loads early
    const unsigned short* Ab = &As[c & 1][(size_t)l * 8];
    #pragma unroll
    for (int k2i = 0; k2i < 2; ++k2i) {
      const int kt = c * 2 + k2i;
      bf16x8 Am[4];
      #pragma unroll
      for (int m = 0; m < 4; ++m)
        Am[m] = *(const bf16x8*)(Ab + (size_t)k2i * 2048 + (size_t)m * 512);
      #pragma unroll
      for (int bn = 0; bn < 4; ++bn) {
        const bf16x8 Bf = *(const bf16x8*)(Bp + ((size_t)kt * 32 + bn) * 512);
        #pragma unroll
        for (int m = 0; m < 4; ++m)
          acc[m][bn] = MFMA16(Am[m], Bf, acc[m][bn]);
      }
    }
    if (c < 9) {                                         // write-late into ping-pong buf
      *(bf16x8*)((c & 1) ? ws0 : ws1) = packcvt(nv0, nv1);
      __syncthreads();
    }
  }

  // ---- GRU epilogue: mem re-read from resident chunks 8/9 (kt 16..19) ----
  const int jcol = (w >> 1) * 32 + (w & 1) * 16 + lc;
  float bg[4];
  #pragma unroll
  for (int g = 0; g < 4; ++g) bg[g] = bcat[w * 64 + g * 16 + lc];
  const unsigned short* membuf = &As[w >> 2][(size_t)((w >> 1) & 1) * 2048];
  const int qp = (w & 1) * 2 + (lc >> 3);
  const int el = lc & 7;

  #pragma unroll
  for (int mt = 0; mt < 4; ++mt) {
    #pragma unroll
    for (int rr = 0; rr < 4; ++rr) {
      const int rloc = mt * 16 + lr * 4 + rr;
      const int grow = rbase + rloc;
      const int n2   = nodes[grow];
      const float aR  = acc[mt][0][rr] + bg[0];
      const float aZ  = acc[mt][1][rr] + bg[1];
      const float aNi = acc[mt][2][rr] + bg[2];
      const float aNh = acc[mt][3][rr] + bg[3];
      const float r_  = fsig(aR);
      const float z_  = fsig(aZ);
      const float n_  = ftanh(aNi + r_ * aNh);
      const float mem = bf2f(membuf[(size_t)(mt * 64 + qp * 16 + (rloc & 15)) * 8 + el]);
      const float h = nfeat[(size_t)n2 * 128 + jcol] + (1.0f - z_) * n_ + z_ * mem;
      hb[(size_t)grow * 128 + jcol] = f2bf(h);
    }
  }
}

// ---------------- k2_fused: gather + KV projection, 1 m-tile/wave ----------------
DEVFN void k2s(const unsigned short* __restrict__ WkvP, int kt, int wn, int l,
               bf16x8 a, f32x4 (&acc)[4]) {
  #pragma unroll
  for (int bn = 0; bn < 4; ++bn) {
    const bf16x8 b = *(const bf16x8*)(WkvP + ((size_t)(kt * 16 + wn * 4 + bn) * 64 + l) * 8);
    acc[bn] = MFMA16(a, b, acc[bn]);
  }
}

__global__ __launch_bounds__(512) void k2_fused(
    const unsigned short* __restrict__ hb, const int* __restrict__ eids,
    const float* __restrict__ dt_nbr, const float* __restrict__ efeat,
    const float* __restrict__ time_w, const float* __restrict__ time_b,
    const unsigned short* __restrict__ WkvP, const float* __restrict__ bkv,
    unsigned short* __restrict__ KVb)
{
  const int w = threadIdx.x >> 6, l = threadIdx.x & 63;
  const int wm = w >> 2, wn = w & 3;           // 2 m-groups x 4 n-groups
  const int lr = l >> 4, lc = l & 15;
  const int t16 = blockIdx.x * 2 + wm;
  const int rbase = t16 * 16;

  int eld = 0; float dld = 0.f;
  if (l < 16) { eld = eids[rbase + l]; dld = dt_nbr[rbase + l]; }
  const int   eid = __shfl(eld, lc);
  const float dt  = __shfl(dld, lc);

  const float* ep = efeat + (size_t)eid * 128 + lr * 8;
  bf16x8 ea[4];
  #pragma unroll
  for (int qq = 0; qq < 4; ++qq)
    ea[qq] = packcvt(((const float4*)(ep + qq * 32))[0], ((const float4*)(ep + qq * 32))[1]);
  const unsigned short* hp = hb + (size_t)(ND_ + rbase + lc) * 128 + lr * 8;
  bf16x8 hh[4];
  #pragma unroll
  for (int qq = 0; qq < 4; ++qq) hh[qq] = *(const bf16x8*)(hp + qq * 32);
  bf16x8 tt[4];
  #pragma unroll
  for (int qq = 0; qq < 4; ++qq) {
    const int c0 = qq * 32 + lr * 8;
    const float4 w0 = ((const float4*)(time_w + c0))[0];
    const float4 w1 = ((const float4*)(time_w + c0))[1];
    const float4 b0 = ((const float4*)(time_b + c0))[0];
    const float4 b1 = ((const float4*)(time_b + c0))[1];
    float4 u, v;
    u.x = __cosf(fmaf(dt, w0.x, b0.x)); u.y = __cosf(fmaf(dt, w0.y, b0.y));
    u.z = __cosf(fmaf(dt, w0.z, b0.z)); u.w = __cosf(fmaf(dt, w0.w, b0.w));
    v.x = __cosf(fmaf(dt, w1.x, b1.x)); v.y = __cosf(fmaf(dt, w1.y, b1.y));
    v.z = __cosf(fmaf(dt, w1.z, b1.z)); v.w = __cosf(fmaf(dt, w1.w, b1.w));
    tt[qq] = packcvt(u, v);
  }

  f32x4 acc[4];
  #pragma unroll
  for (int bn = 0; bn < 4; ++bn) acc[bn] = (f32x4){0.f, 0.f, 0.f, 0.f};

  #pragma unroll
  for (int qq = 0; qq < 4; ++qq) k2s(WkvP, qq, wn, l, hh[qq], acc);
  #pragma unroll
  for (int qq = 0; qq < 4; ++qq) k2s(WkvP, 4 + qq, wn, l, ea[qq], acc);
  #pragma unroll
  for (int qq = 0; qq < 4; ++qq) k2s(WkvP, 8 + qq, wn, l, tt[qq], acc);

  float bb[4];
  #pragma unroll
  for (int bn = 0; bn < 4; ++bn) bb[bn] = bkv[wn * 64 + bn * 16 + lc];

  #pragma unroll
  for (int rr = 0; rr < 4; ++rr) {
    const size_t grow = (size_t)(rbase + lr * 4 + rr);
    #pragma unroll
    for (int bn = 0; bn < 4; ++bn)
      KVb[grow * 256 + wn * 64 + bn * 16 + lc] = f2bf(acc[bn][rr] + bb[bn]);
  }
}

// ---------------- kQ_gemm: Q = dst_h @ wq[:, :128]^T + qzero -> Qb (bf16) ----------------
__global__ __launch_bounds__(512) void kQ_gemm(
    const unsigned short* __restrict__ hb, const unsigned short* __restrict__ WqB,
    const float* __restrict__ qzero, unsigned short* __restrict__ Qb)
{
  const int w = threadIdx.x >> 6, l = threadIdx.x & 63;
  const int wm = w >> 2, wn = w & 3;
  const int lr = l >> 4, lc = l & 15;
  const int t16base = blockIdx.x * 4 + wm * 2;
  const unsigned short* Ar0 = hb + (size_t)(t16base * 16 + lc) * 128 + lr * 8;
  const unsigned short* Ar1 = Ar0 + 16 * 128;

  f32x4 acc[2][2];
  #pragma unroll
  for (int m = 0; m < 2; ++m)
    #pragma unroll
    for (int bn = 0; bn < 2; ++bn) acc[m][bn] = (f32x4){0.f, 0.f, 0.f, 0.f};

  #pragma unroll
  for (int kt = 0; kt < 4; ++kt) {
    const bf16x8 a0 = *(const bf16x8*)(Ar0 + kt * 32);
    const bf16x8 a1 = *(const bf16x8*)(Ar1 + kt * 32);
    #pragma unroll
    for (int bn = 0; bn < 2; ++bn) {
      const bf16x8 b = *(const bf16x8*)(WqB + ((size_t)(kt * 8 + wn * 2 + bn) * 64 + l) * 8);
      acc[0][bn] = MFMA16(a0, b, acc[0][bn]);
      acc[1][bn] = MFMA16(a1, b, acc[1][bn]);
    }
  }

  #pragma unroll
  for (int mt = 0; mt < 2; ++mt)
    #pragma unroll
    for (int rr = 0; rr < 4; ++rr) {
      const int row = (t16base + mt) * 16 + lr * 4 + rr;
      #pragma unroll
      for (int bn = 0; bn < 2; ++bn) {
        const int col = (wn * 2 + bn) * 16 + lc;
        Qb[(size_t)row * 128 + col] = f2bf(acc[mt][bn][rr] + qzero[col]);
      }
    }
}

// ---------------- kAtt: per-row 2-head attention over 10 neighbors -> aggb (bf16) ----------------
__global__ __launch_bounds__(256) void kAtt(
    const unsigned short* __restrict__ Qb, const unsigned short* __restrict__ KVb,
    unsigned short* __restrict__ aggb)
{
  const int w = threadIdx.x >> 6, l = threadIdx.x & 63;
  const int i = blockIdx.x * 4 + w;
  const float q0 = bf2f(Qb[(size_t)i * 128 + l]);
  const float q1 = bf2f(Qb[(size_t)i * 128 + 64 + l]);
  const unsigned short* base = KVb + (size_t)i * K_ * 256;

  float s0[K_], s1[K_], v0[K_], v1[K_];
  #pragma unroll
  for (int kk = 0; kk < K_; ++kk) {
    const unsigned short* rp = base + kk * 256;
    const float k0 = bf2f(rp[l]);
    const float k1 = bf2f(rp[64 + l]);
    v0[kk] = bf2f(rp[128 + l]);
    v1[kk] = bf2f(rp[192 + l]);
    float p0 = q0 * k0, p1 = q1 * k1;
    #pragma unroll
    for (int t = 32; t; t >>= 1) { p0 += __shfl_xor(p0, t); p1 += __shfl_xor(p1, t); }
    s0[kk] = p0; s1[kk] = p1;
  }
  float m0 = s0[0], m1 = s1[0];
  #pragma unroll
  for (int kk = 1; kk < K_; ++kk) { m0 = fmaxf(m0, s0[kk]); m1 = fmaxf(m1, s1[kk]); }
  float sum0 = 0.f, sum1 = 0.f, a0 = 0.f, a1 = 0.f;
  #pragma unroll
  for (int kk = 0; kk < K_; ++kk) {
    const float e0 = __expf(s0[kk] - m0);
    const float e1 = __expf(s1[kk] - m1);
    sum0 += e0; sum1 += e1;
    a0 += e0 * v0[kk]; a1 += e1 * v1[kk];
  }
  aggb[(size_t)i * 128 + l]      = f2bf(__fdividef(a0, sum0));
  aggb[(size_t)i * 128 + 64 + l] = f2bf(__fdividef(a1, sum1));
}

// ---------------- kO_ln: out-proj + ReLU + LayerNorm fused -> emb (fp32) ----------------
__global__ __launch_bounds__(512) void kO_ln(
    const unsigned short* __restrict__ hb, const unsigned short* __restrict__ aggb,
    const unsigned short* __restrict__ WoB, const float* __restrict__ bo,
    const float* __restrict__ ln_g, const float* __restrict__ ln_b,
    float* __restrict__ emb)
{
  __shared__ float ps[64][4], pq[64][4];
  const int w = threadIdx.x >> 6, l = threadIdx.x & 63;
  const int wm = w >> 2, wn = w & 3;
  const int lr = l >> 4, lc = l & 15;
  const int t16base = blockIdx.x * 4 + wm * 2;
  const unsigned short* Ah0 = hb   + (size_t)(t16base * 16 + lc) * 128 + lr * 8;
  const unsigned short* Ah1 = Ah0 + 16 * 128;
  const unsigned short* Ag0 = aggb + (size_t)(t16base * 16 + lc) * 128 + lr * 8;
  const unsigned short* Ag1 = Ag0 + 16 * 128;

  f32x4 acc[2][2];
  #pragma unroll
  for (int m = 0; m < 2; ++m)
    #pragma unroll
    for (int bn = 0; bn < 2; ++bn) acc[m][bn] = (f32x4){0.f, 0.f, 0.f, 0.f};

  #pragma unroll
  for (int kt = 0; kt < 8; ++kt) {
    const bf16x8 a0 = (kt < 4) ? *(const bf16x8*)(Ah0 + kt * 32)
                               : *(const bf16x8*)(Ag0 + (kt - 4) * 32);
    const bf16x8 a1 = (kt < 4) ? *(const bf16x8*)(Ah1 + kt * 32)
                               : *(const bf16x8*)(Ag1 + (kt - 4) * 32);
    #pragma unroll
    for (int bn = 0; bn < 2; ++bn) {
      const bf16x8 b = *(const bf16x8*)(WoB + ((size_t)(kt * 8 + wn * 2 + bn) * 64 + l) * 8);
      acc[0][bn] = MFMA16(a0, b, acc[0][bn]);
      acc[1][bn] = MFMA16(a1, b, acc[1][bn]);
    }
  }

  const int c0 = (wn * 2) * 16 + lc, c1 = c0 + 16;
  const float b0v = bo[c0], b1v = bo[c1];
  float xv0[2][4], xv1[2][4];
  #pragma unroll
  for (int mt = 0; mt < 2; ++mt)
    #pragma unroll
    for (int rr = 0; rr < 4; ++rr) {
      const float x0 = fmaxf(acc[mt][0][rr] + b0v, 0.f);
      const float x1 = fmaxf(acc[mt][1][rr] + b1v, 0.f);
      xv0[mt][rr] = x0; xv1[mt][rr] = x1;
      float s = x0 + x1, q = x0 * x0 + x1 * x1;
      #pragma unroll
      for (int t = 8; t; t >>= 1) { s += __shfl_xor(s, t); q += __shfl_xor(q, t); }
      const int rloc = (wm * 2 + mt) * 16 + lr * 4 + rr;
      if (lc == 0) { ps[rloc][wn] = s; pq[rloc][wn] = q; }
    }
  __syncthreads();
  const float g0 = ln_g[c0], g1 = ln_g[c1], lb0 = ln_b[c0], lb1 = ln_b[c1];
  #pragma unroll
  for (int mt = 0; mt < 2; ++mt)
    #pragma unroll
    for (int rr = 0; rr < 4; ++rr) {
      const int rloc = (wm * 2 + mt) * 16 + lr * 4 + rr;
      const int row  = blockIdx.x * 64 + rloc;
      const float sum = ps[rloc][0] + ps[rloc][1] + ps[rloc][2] + ps[rloc][3];
      const float sq  = pq[rloc][0] + pq[rloc][1] + pq[rloc][2] + pq[rloc][3];
      const float mu  = sum * (1.0f / 128.0f);
      const float var = sq * (1.0f / 128.0f) - mu * mu;
      const float rs  = rsqrtf(var + 1e-5f);
      emb[(size_t)row * 128 + c0] = g0 * (xv0[mt][rr] - mu) * rs + lb0;
      emb[(size_t)row * 128 + c1] = g1 * (xv1[mt][rr] - mu) * rs + lb1;
    }
}

// ---------------- k3: edge predictor -> out[B][2] ----------------
__global__ __launch_bounds__(128) void k3_ep(
    const float* __restrict__ emb, const float4* __restrict__ SwP,
    const float4* __restrict__ DwP, const float* __restrict__ ep_sb,
    const float* __restrict__ ep_db, const float* __restrict__ ep_ow,
    const float* __restrict__ ep_ob, float* __restrict__ out)
{
  __shared__ float se[128], de[128], ne[128];
  __shared__ float redp[2], redn[2];
  const int c = threadIdx.x;
  const int i = blockIdx.x;
  se[c] = emb[(size_t)i * 128 + c];
  de[c] = emb[(size_t)(B_ + i) * 128 + c];
  ne[c] = emb[(size_t)(2 * B_ + i) * 128 + c];
  __syncthreads();
  float sacc = ep_sb[c], dacc = ep_db[c], nacc = ep_db[c];
  for (int k4 = 0; k4 < 32; ++k4) {
    const float4 sw = SwP[k4 * 128 + c];
    const float4 dw = DwP[k4 * 128 + c];
    sacc = dot4(((const float4*)se)[k4], sw, sacc);
    dacc = dot4(((const float4*)de)[k4], dw, dacc);
    nacc = dot4(((const float4*)ne)[k4], dw, nacc);
  }
  const float ow = ep_ow[c];
  float pp = fmaxf(sacc + dacc, 0.f) * ow;
  float pn = fmaxf(sacc + nacc, 0.f) * ow;
  for (int t = 32; t; t >>= 1) { pp += __shfl_xor(pp, t); pn += __shfl_xor(pn, t); }
  if ((c & 63) == 0) { redp[c >> 6] = pp; redn[c >> 6] = pn; }
  __syncthreads();
  if (c == 0) {
    const float ob = ep_ob[0];
    out[i * 2]     = redp[0] + redp[1] + ob;
    out[i * 2 + 1] = redn[0] + redn[1] + ob;
  }
}

// ---------------- launch ----------------
extern "C" void kernel_launch(void* const* d_in, const int* in_sizes, int n_in,
                              void* d_out, int out_size, void* d_ws, size_t ws_size,
                              hipStream_t stream) {
  const int*   nodes     = (const int*)d_in[0];
  const int*   eids      = (const int*)d_in[1];
  const float* dt_nbr    = (const float*)d_in[2];
  const float* nfeat     = (const float*)d_in[3];
  const float* mem_data  = (const float*)d_in[4];
  const float* mem_time  = (const float*)d_in[5];
  const float* mail_data = (const float*)d_in[6];
  const float* mail_time = (const float*)d_in[7];
  const float* efeat     = (const float*)d_in[8];
  const float* time_w    = (const float*)d_in[9];
  const float* time_b    = (const float*)d_in[10];
  const float* gru_w_ih  = (const float*)d_in[11];
  const float* gru_w_hh  = (const float*)d_in[12];
  const float* gru_b_ih  = (const float*)d_in[13];
  const float* gru_b_hh  = (const float*)d_in[14];
  const float* wq        = (const float*)d_in[15];
  const float* bq        = (const float*)d_in[16];
  const float* wk        = (const float*)d_in[17];
  const float* bk        = (const float*)d_in[18];
  const float* wv        = (const float*)d_in[19];
  const float* bv        = (const float*)d_in[20];
  const float* wo        = (const float*)d_in[21];
  const float* bo        = (const float*)d_in[22];
  const float* ln_g      = (const float*)d_in[23];
  const float* ln_b      = (const float*)d_in[24];
  const float* ep_sw     = (const float*)d_in[25];
  const float* ep_sb     = (const float*)d_in[26];
  const float* ep_dw     = (const float*)d_in[27];
  const float* ep_db     = (const float*)d_in[28];
  const float* ep_ow     = (const float*)d_in[29];
  const float* ep_ob     = (const float*)d_in[30];
  float* out = (float*)d_out;
  float* ws  = (float*)d_ws;

  unsigned short* Qb    = (unsigned short*)(ws + OFF_QB);
  unsigned short* aggb  = (unsigned short*)(ws + OFF_AGG);
  unsigned short* hb    = (unsigned short*)(ws + OFF_HB);
  unsigned short* KVb   = (unsigned short*)(ws + OFF_KVB);
  float*          emb   = ws + OFF_EMB;
  unsigned short* WcatP = (unsigned short*)(ws + OFF_WCAT);
  unsigned short* WkvP  = (unsigned short*)(ws + OFF_WKV);
  float*          bcat  = ws + OFF_BCAT;
  float*          bkv   = ws + OFF_BKV;
  unsigned short* WqB   = (unsigned short*)(ws + OFF_WQB);
  unsigned short* WoB   = (unsigned short*)(ws + OFF_WOB);
  float4*         SwP   = (float4*)(ws + OFF_SWP);
  float4*         DwP   = (float4*)(ws + OFF_DWP);
  float*          qzero = ws + OFF_QZ;

  k0_all<<<1892, 256, 0, stream>>>(gru_w_ih, gru_w_hh, wk, wv, wq, wo, ep_sw, ep_dw,
                                   gru_b_ih, gru_b_hh, bk, bv, time_b, bq,
                                   WcatP, WkvP, WqB, WoB, SwP, DwP, bcat, bkv, qzero);
  k1_fused<<<NTOT / 64, 512, 0, stream>>>(nodes, mail_data, mem_data, mail_time,
                                          mem_time, time_w, time_b, WcatP, bcat,
                                          nfeat, hb);
  k2_fused<<<RKV / 32, 512, 0, stream>>>(hb, eids, dt_nbr, efeat, time_w, time_b,
                                         WkvP, bkv, KVb);
  kQ_gemm<<<ND_ / 64, 512, 0, stream>>>(hb, WqB, qzero, Qb);
  kAtt<<<ND_ / 4, 256, 0, stream>>>(Qb, KVb, aggb);
  kO_ln<<<ND_ / 64, 512, 0, stream>>>(hb, aggb, WoB, bo, ln_g, ln_b, emb);
  k3_ep<<<B_, 128, 0, stream>>>(emb, SwP, DwP, ep_sb, ep_db, ep_ow, ep_ob, out);
}

// Round 15
// 381.090 us; speedup vs baseline: 1.1235x; 1.1235x over previous
//
#include <hip/hip_runtime.h>

// ---------------- problem constants ----------------
constexpr int ND_   = 12288;           // 3*B
constexpr int K_    = 10;
constexpr int NTOT  = ND_ * (1 + K_);  // 135168
constexpr int B_    = 4096;
constexpr int RKV   = ND_ * K_;        // 122880

// ---------------- ws layout (float offsets) ----------------
constexpr size_t OFF_QB   = 0;          // ushort[ND_*128]
constexpr size_t OFF_AGG  = 786432;     // ushort[ND_*128]
constexpr size_t OFF_HB   = 43253760;   // ushort[NTOT*128] -> 8,650,752 fl
constexpr size_t OFF_KVB  = 51904512;   // ushort[RKV*256]  -> 15,728,640 fl
constexpr size_t OFF_EMB  = 67633152;   // float[ND_*128]   -> 1,572,864
constexpr size_t OFF_WCAT = 69206016;   // ushort[640*512]  -> 163,840 fl
constexpr size_t OFF_WKV  = 69369856;   // ushort[384*256]  -> 49,152 fl
constexpr size_t OFF_BCAT = 69419008;   // float[512]
constexpr size_t OFF_BKV  = 69419520;   // float[256]
constexpr size_t OFF_WQB  = 69419776;   // ushort[128*128]
constexpr size_t OFF_WOB  = 69427968;   // ushort[256*128]
constexpr size_t OFF_SWP  = 69444352;   // float4[32*128]
constexpr size_t OFF_DWP  = 69460736;   // float4[32*128]
constexpr size_t OFF_QZ   = 69477120;   // float[128]

#define DEVFN __device__ __forceinline__

typedef __attribute__((ext_vector_type(8))) short bf16x8;
typedef __attribute__((ext_vector_type(4))) float f32x4;
#define MFMA16(a, b, c) __builtin_amdgcn_mfma_f32_16x16x32_bf16((a), (b), (c), 0, 0, 0)

DEVFN unsigned short f2bf(float x) {           // RNE float->bf16 (scalar path)
  unsigned int u = __float_as_uint(x);
  u = (u + 0x7FFFu + ((u >> 16) & 1u)) >> 16;
  return (unsigned short)u;
}
DEVFN float bf2f(unsigned short h) { return __uint_as_float(((unsigned int)h) << 16); }

// packed RNE f32->bf16 via HW cvt
DEVFN bf16x8 packcvt(float4 a, float4 b) {
  union { unsigned int u[4]; bf16x8 v; } r;
  asm("v_cvt_pk_bf16_f32 %0, %1, %2" : "=v"(r.u[0]) : "v"(a.x), "v"(a.y));
  asm("v_cvt_pk_bf16_f32 %0, %1, %2" : "=v"(r.u[1]) : "v"(a.z), "v"(a.w));
  asm("v_cvt_pk_bf16_f32 %0, %1, %2" : "=v"(r.u[2]) : "v"(b.x), "v"(b.y));
  asm("v_cvt_pk_bf16_f32 %0, %1, %2" : "=v"(r.u[3]) : "v"(b.z), "v"(b.w));
  return r.v;
}

DEVFN float dot4(const float4 a, const float4 b, float acc) {
  acc = fmaf(a.x, b.x, acc);
  acc = fmaf(a.y, b.y, acc);
  acc = fmaf(a.z, b.z, acc);
  acc = fmaf(a.w, b.w, acc);
  return acc;
}
// fast transcendentals (error ~1e-6 rel, << bf16 quantization)
DEVFN float fsig(float x)  { return __fdividef(1.0f, 1.0f + __expf(-x)); }
DEVFN float ftanh(float x) {
  x = fminf(fmaxf(x, -15.0f), 15.0f);
  const float t = __expf(2.0f * x);
  return __fdividef(t - 1.0f, t + 1.0f);
}

// ---------------- k0_all: all weight/bias packs in one launch ----------------
// Wcat c'-mapping: c' = q*128 + jb*64 + g*16 + t, channel j = q*32 + jb*16 + t, g in {R,Z,Ni,Nh}.
// k<512: w_ih (R/Z/Ni; zero Nh); k>=512: w_hh (R/Z/Nh; zero Ni).
__global__ void k0_all(const float* __restrict__ w_ih, const float* __restrict__ w_hh,
                       const float* __restrict__ wk,   const float* __restrict__ wv,
                       const float* __restrict__ wq,   const float* __restrict__ wo,
                       const float* __restrict__ sw,   const float* __restrict__ dwm,
                       const float* __restrict__ b_ih, const float* __restrict__ b_hh,
                       const float* __restrict__ bk,   const float* __restrict__ bv,
                       const float* __restrict__ time_b, const float* __restrict__ bq,
                       unsigned short* __restrict__ WcatP, unsigned short* __restrict__ WkvP,
                       unsigned short* __restrict__ WqB,   unsigned short* __restrict__ WoB,
                       float4* __restrict__ SwP, float4* __restrict__ DwP,
                       float* __restrict__ bcat, float* __restrict__ bkv,
                       float* __restrict__ qzero)
{
  int gid = blockIdx.x * 256 + threadIdx.x;
  if (gid < 327680) {                    // WcatP: 20 kt x 32 nt
    int f = gid >> 9, idx = gid & 511;
    int l = idx >> 3, j8 = idx & 7;
    int kt = f >> 5, nt = f & 31;
    int k = kt * 32 + (l >> 4) * 8 + j8;
    int c = nt * 16 + (l & 15);
    int q = c >> 7, jb = (c >> 6) & 1, g = (c >> 4) & 3, j = q * 32 + jb * 16 + (c & 15);
    float w;
    if (g == 0)      w = (k < 512) ? w_ih[(size_t)j * 512 + k]         : w_hh[(size_t)j * 128 + (k - 512)];
    else if (g == 1) w = (k < 512) ? w_ih[(size_t)(128 + j) * 512 + k] : w_hh[(size_t)(128 + j) * 128 + (k - 512)];
    else if (g == 2) w = (k < 512) ? w_ih[(size_t)(256 + j) * 512 + k] : 0.0f;
    else             w = (k < 512) ? 0.0f : w_hh[(size_t)(256 + j) * 128 + (k - 512)];
    WcatP[gid] = f2bf(w);
    return;
  }
  gid -= 327680;
  if (gid < 98304) {                     // WkvP: 12 kt x 16 nt (K|V)
    int f = gid >> 9, idx = gid & 511;
    int l = idx >> 3, j8 = idx & 7;
    int kt = f >> 4, nt = f & 15;
    int k = kt * 32 + (l >> 4) * 8 + j8;
    int c = nt * 16 + (l & 15);
    float w = (c < 128) ? wk[(size_t)c * 384 + k] : wv[(size_t)(c - 128) * 384 + k];
    WkvP[gid] = f2bf(w);
    return;
  }
  gid -= 98304;
  if (gid < 49152) {                     // WqB (4x8) then WoB (8x8)
    if (gid < 16384) {
      int f = gid >> 9, idx = gid & 511;
      int l = idx >> 3, j8 = idx & 7;
      int kt = f >> 3, nt = f & 7;
      int k = kt * 32 + (l >> 4) * 8 + j8;
      int c = nt * 16 + (l & 15);
      WqB[gid] = f2bf(wq[(size_t)c * 256 + k]);
    } else {
      int g2 = gid - 16384;
      int f = g2 >> 9, idx = g2 & 511;
      int l = idx >> 3, j8 = idx & 7;
      int kt = f >> 3, nt = f & 7;
      int k = kt * 32 + (l >> 4) * 8 + j8;
      int c = nt * 16 + (l & 15);
      WoB[g2] = f2bf(wo[(size_t)c * 256 + k]);
    }
    return;
  }
  gid -= 49152;
  if (gid < 8960) {                      // SwP / DwP / bcat / bkv
    if (gid < 4096) {
      int k4 = gid / 128, c = gid % 128;
      const float* s = sw + c * 128 + 4 * k4;
      SwP[gid] = make_float4(s[0], s[1], s[2], s[3]);
    } else if (gid < 8192) {
      int id = gid - 4096;
      int k4 = id / 128, c = id % 128;
      const float* s = dwm + c * 128 + 4 * k4;
      DwP[id] = make_float4(s[0], s[1], s[2], s[3]);
    } else if (gid < 8704) {
      int id = gid - 8192;
      int q = id >> 7, jb = (id >> 6) & 1, g = (id >> 4) & 3, lcc = id & 15;
      int j = q * 32 + jb * 16 + lcc;
      float b;
      if (g == 0)      b = b_ih[j] + b_hh[j];
      else if (g == 1) b = b_ih[128 + j] + b_hh[128 + j];
      else if (g == 2) b = b_ih[256 + j];
      else             b = b_hh[256 + j];
      bcat[id] = b;
    } else {
      int id = gid - 8704;
      bkv[id] = (id < 128) ? bk[id] : bv[id - 128];
    }
    return;
  }
  gid -= 8960;
  if (gid < 128) {                       // qzero (accurate cos, one-off)
    float acc = bq[gid];
    for (int k = 0; k < 128; ++k)
      acc = fmaf(cosf(time_b[k]), wq[gid * 256 + 128 + k], acc);
    qzero[gid] = acc;
  }
}

// ---------------- k1_fused: coalesced row-burst staged MFMA GRU ----------------
// 32 rows/block, 512 thr. STAGE: 16-lane group owns one row; lane j reads 64B
// CONTIGUOUS (cols j*16..+16 of [mail|mem]) — full 2KB burst per row (was 32B
// uncoalesced random). kt-row swizzle row'=(r15+kt)&15 keeps stage writes <=4-way;
// MFMA reads stay conflict-free (64 distinct slots/1KB per wave). nfeat staged to
// LDS coalesced post-MFMA (was 8 scalar gathers/thread).
__global__ __launch_bounds__(512, 4) void k1_fused(
    const int* __restrict__ nodes, const float* __restrict__ mail_data,
    const float* __restrict__ mem_data, const float* __restrict__ mail_time,
    const float* __restrict__ mem_time, const float* __restrict__ time_w,
    const float* __restrict__ time_b, const unsigned short* __restrict__ WcatP,
    const float* __restrict__ bcat, const float* __restrict__ nfeat,
    unsigned short* __restrict__ hb)
{
  __shared__ unsigned short As[20 * 1024];     // 40KB; first 17.4KB reused for nfeat later
  const int tid = threadIdx.x;
  const int rbase = blockIdx.x * 32;

  const int r = tid >> 4, j = tid & 15;        // row [0,32), lane-in-group
  const int n = nodes[rbase + r];
  const int half = r >> 4, r15 = r & 15;

  // ---- stage phase: coalesced row bursts ----
  {
    const float drow = mail_time[n] - mem_time[n];
    const float* mailp = mail_data + (size_t)n * 384;
    const float* memp  = mem_data  + (size_t)n * 128;

    // chunk 0: cols j*16 (mail, kt = j>>1, q0 = (j&1)*2)
    {
      const float* s = mailp + j * 16;
      const float4 a = *(const float4*)s, b = *(const float4*)(s + 4);
      const float4 c = *(const float4*)(s + 8), d = *(const float4*)(s + 12);
      const int kt = j >> 1, q0 = (j & 1) * 2;
      const int rowp = (r15 + kt) & 15;
      unsigned short* wb = As + (size_t)kt * 1024 + (size_t)(half * 64 + q0 * 16 + rowp) * 8;
      *(bf16x8*)wb = packcvt(a, b);
      *(bf16x8*)(wb + 128) = packcvt(c, d);
    }
    // chunk 1: j<8 -> mail cols 256+j*16 (kt=8+(j>>1)); j>=8 -> mem cols (j-8)*16 (kt=12+(j>>1))
    {
      const float* s = (j < 8) ? (mailp + 256 + j * 16) : (memp + (j - 8) * 16);
      const float4 a = *(const float4*)s, b = *(const float4*)(s + 4);
      const float4 c = *(const float4*)(s + 8), d = *(const float4*)(s + 12);
      const int kt = (j < 8) ? (8 + (j >> 1)) : (12 + (j >> 1));
      const int q0 = (j & 1) * 2;
      const int rowp = (r15 + kt) & 15;
      unsigned short* wb = As + (size_t)kt * 1024 + (size_t)(half * 64 + q0 * 16 + rowp) * 8;
      *(bf16x8*)wb = packcvt(a, b);
      *(bf16x8*)(wb + 128) = packcvt(c, d);
    }
    // tenc: cols 384 + j*8 -> kt = 12 + (j>>2), q = j&3
    {
      const float4 w0 = *(const float4*)(time_w + j * 8);
      const float4 w1 = *(const float4*)(time_w + j * 8 + 4);
      const float4 b0 = *(const float4*)(time_b + j * 8);
      const float4 b1 = *(const float4*)(time_b + j * 8 + 4);
      float4 u, v;
      u.x = __cosf(fmaf(drow, w0.x, b0.x)); u.y = __cosf(fmaf(drow, w0.y, b0.y));
      u.z = __cosf(fmaf(drow, w0.z, b0.z)); u.w = __cosf(fmaf(drow, w0.w, b0.w));
      v.x = __cosf(fmaf(drow, w1.x, b1.x)); v.y = __cosf(fmaf(drow, w1.y, b1.y));
      v.z = __cosf(fmaf(drow, w1.z, b1.z)); v.w = __cosf(fmaf(drow, w1.w, b1.w));
      const int kt = 12 + (j >> 2), q = j & 3;
      const int rowp = (r15 + kt) & 15;
      unsigned short* wb = As + (size_t)kt * 1024 + (size_t)(half * 64 + q * 16 + rowp) * 8;
      *(bf16x8*)wb = packcvt(u, v);
    }
  }
  __syncthreads();

  // ---- MFMA phase: wave w -> nt w*4..w*4+3; reads swizzled rows ----
  const int w = tid >> 6, l = tid & 63;
  const int lr = l >> 4, lc = l & 15;
  const unsigned short* Bp = WcatP + (size_t)(w * 4) * 512 + l * 8;

  f32x4 acc[2][4];
  #pragma unroll
  for (int m = 0; m < 2; ++m)
    #pragma unroll
    for (int bn = 0; bn < 4; ++bn) acc[m][bn] = (f32x4){0.f, 0.f, 0.f, 0.f};

  #pragma unroll
  for (int kt = 0; kt < 20; ++kt) {
    const int rowp = (lc + kt) & 15;
    const unsigned short* Ab = As + (size_t)kt * 1024 + (size_t)(lr * 16 + rowp) * 8;
    const bf16x8 A0 = *(const bf16x8*)Ab;
    const bf16x8 A1 = *(const bf16x8*)(Ab + 512);
    #pragma unroll
    for (int bn = 0; bn < 4; ++bn) {
      const bf16x8 Bf = *(const bf16x8*)(Bp + ((size_t)kt * 32 + bn) * 512);
      acc[0][bn] = MFMA16(A0, Bf, acc[0][bn]);
      acc[1][bn] = MFMA16(A1, Bf, acc[1][bn]);
    }
  }
  __syncthreads();                       // protect As[0..] before nfeat overwrite

  // ---- stage nfeat coalesced into LDS (stride-136 floats per row) ----
  float* const nf = (float*)As;          // 32*136*4 = 17.4KB (mem region kt16-19 at 32KB+ untouched)
  {
    const float* np = nfeat + (size_t)n * 128 + j * 8;
    const float4 x = *(const float4*)np, y = *(const float4*)(np + 4);
    *(float4*)(nf + (size_t)r * 136 + j * 8)     = x;
    *(float4*)(nf + (size_t)r * 136 + j * 8 + 4) = y;
  }
  __syncthreads();

  // ---- GRU epilogue: mem + nfeat from LDS ----
  const int jcol = (w >> 1) * 32 + (w & 1) * 16 + lc;
  float bg[4];
  #pragma unroll
  for (int g = 0; g < 4; ++g) bg[g] = bcat[w * 64 + g * 16 + lc];
  const int memkt = 16 + (w >> 1);
  const int qp = (w & 1) * 2 + (lc >> 3);
  const int el = lc & 7;

  #pragma unroll
  for (int mt = 0; mt < 2; ++mt) {
    #pragma unroll
    for (int rr = 0; rr < 4; ++rr) {
      const int rloc = mt * 16 + lr * 4 + rr;
      const int grow = rbase + rloc;
      const int rowp = ((rloc & 15) + memkt) & 15;
      const float aR  = acc[mt][0][rr] + bg[0];
      const float aZ  = acc[mt][1][rr] + bg[1];
      const float aNi = acc[mt][2][rr] + bg[2];
      const float aNh = acc[mt][3][rr] + bg[3];
      const float r_  = fsig(aR);
      const float z_  = fsig(aZ);
      const float n_  = ftanh(aNi + r_ * aNh);
      const float mem = bf2f(As[(size_t)memkt * 1024 +
                                (size_t)(mt * 64 + qp * 16 + rowp) * 8 + el]);
      const float h = nf[(size_t)rloc * 136 + jcol] + (1.0f - z_) * n_ + z_ * mem;
      hb[(size_t)grow * 128 + jcol] = f2bf(h);
    }
  }
}

// ---------------- k2_fused: gather + KV projection, 1 m-tile/wave ----------------
DEVFN void k2s(const unsigned short* __restrict__ WkvP, int kt, int wn, int l,
               bf16x8 a, f32x4 (&acc)[4]) {
  #pragma unroll
  for (int bn = 0; bn < 4; ++bn) {
    const bf16x8 b = *(const bf16x8*)(WkvP + ((size_t)(kt * 16 + wn * 4 + bn) * 64 + l) * 8);
    acc[bn] = MFMA16(a, b, acc[bn]);
  }
}

__global__ __launch_bounds__(512) void k2_fused(
    const unsigned short* __restrict__ hb, const int* __restrict__ eids,
    const float* __restrict__ dt_nbr, const float* __restrict__ efeat,
    const float* __restrict__ time_w, const float* __restrict__ time_b,
    const unsigned short* __restrict__ WkvP, const float* __restrict__ bkv,
    unsigned short* __restrict__ KVb)
{
  const int w = threadIdx.x >> 6, l = threadIdx.x & 63;
  const int wm = w >> 2, wn = w & 3;           // 2 m-groups x 4 n-groups
  const int lr = l >> 4, lc = l & 15;
  const int t16 = blockIdx.x * 2 + wm;
  const int rbase = t16 * 16;

  int eld = 0; float dld = 0.f;
  if (l < 16) { eld = eids[rbase + l]; dld = dt_nbr[rbase + l]; }
  const int   eid = __shfl(eld, lc);
  const float dt  = __shfl(dld, lc);

  const float* ep = efeat + (size_t)eid * 128 + lr * 8;
  bf16x8 ea[4];
  #pragma unroll
  for (int qq = 0; qq < 4; ++qq)
    ea[qq] = packcvt(((const float4*)(ep + qq * 32))[0], ((const float4*)(ep + qq * 32))[1]);
  const unsigned short* hp = hb + (size_t)(ND_ + rbase + lc) * 128 + lr * 8;
  bf16x8 hh[4];
  #pragma unroll
  for (int qq = 0; qq < 4; ++qq) hh[qq] = *(const bf16x8*)(hp + qq * 32);
  bf16x8 tt[4];
  #pragma unroll
  for (int qq = 0; qq < 4; ++qq) {
    const int c0 = qq * 32 + lr * 8;
    const float4 w0 = ((const float4*)(time_w + c0))[0];
    const float4 w1 = ((const float4*)(time_w + c0))[1];
    const float4 b0 = ((const float4*)(time_b + c0))[0];
    const float4 b1 = ((const float4*)(time_b + c0))[1];
    float4 u, v;
    u.x = __cosf(fmaf(dt, w0.x, b0.x)); u.y = __cosf(fmaf(dt, w0.y, b0.y));
    u.z = __cosf(fmaf(dt, w0.z, b0.z)); u.w = __cosf(fmaf(dt, w0.w, b0.w));
    v.x = __cosf(fmaf(dt, w1.x, b1.x)); v.y = __cosf(fmaf(dt, w1.y, b1.y));
    v.z = __cosf(fmaf(dt, w1.z, b1.z)); v.w = __cosf(fmaf(dt, w1.w, b1.w));
    tt[qq] = packcvt(u, v);
  }

  f32x4 acc[4];
  #pragma unroll
  for (int bn = 0; bn < 4; ++bn) acc[bn] = (f32x4){0.f, 0.f, 0.f, 0.f};

  #pragma unroll
  for (int qq = 0; qq < 4; ++qq) k2s(WkvP, qq, wn, l, hh[qq], acc);
  #pragma unroll
  for (int qq = 0; qq < 4; ++qq) k2s(WkvP, 4 + qq, wn, l, ea[qq], acc);
  #pragma unroll
  for (int qq = 0; qq < 4; ++qq) k2s(WkvP, 8 + qq, wn, l, tt[qq], acc);

  float bb[4];
  #pragma unroll
  for (int bn = 0; bn < 4; ++bn) bb[bn] = bkv[wn * 64 + bn * 16 + lc];

  #pragma unroll
  for (int rr = 0; rr < 4; ++rr) {
    const size_t grow = (size_t)(rbase + lr * 4 + rr);
    #pragma unroll
    for (int bn = 0; bn < 4; ++bn)
      KVb[grow * 256 + wn * 64 + bn * 16 + lc] = f2bf(acc[bn][rr] + bb[bn]);
  }
}

// ---------------- kQ_gemm: Q = dst_h @ wq[:, :128]^T + qzero -> Qb (bf16) ----------------
__global__ __launch_bounds__(512) void kQ_gemm(
    const unsigned short* __restrict__ hb, const unsigned short* __restrict__ WqB,
    const float* __restrict__ qzero, unsigned short* __restrict__ Qb)
{
  const int w = threadIdx.x >> 6, l = threadIdx.x & 63;
  const int wm = w >> 2, wn = w & 3;
  const int lr = l >> 4, lc = l & 15;
  const int t16base = blockIdx.x * 4 + wm * 2;
  const unsigned short* Ar0 = hb + (size_t)(t16base * 16 + lc) * 128 + lr * 8;
  const unsigned short* Ar1 = Ar0 + 16 * 128;

  f32x4 acc[2][2];
  #pragma unroll
  for (int m = 0; m < 2; ++m)
    #pragma unroll
    for (int bn = 0; bn < 2; ++bn) acc[m][bn] = (f32x4){0.f, 0.f, 0.f, 0.f};

  #pragma unroll
  for (int kt = 0; kt < 4; ++kt) {
    const bf16x8 a0 = *(const bf16x8*)(Ar0 + kt * 32);
    const bf16x8 a1 = *(const bf16x8*)(Ar1 + kt * 32);
    #pragma unroll
    for (int bn = 0; bn < 2; ++bn) {
      const bf16x8 b = *(const bf16x8*)(WqB + ((size_t)(kt * 8 + wn * 2 + bn) * 64 + l) * 8);
      acc[0][bn] = MFMA16(a0, b, acc[0][bn]);
      acc[1][bn] = MFMA16(a1, b, acc[1][bn]);
    }
  }

  #pragma unroll
  for (int mt = 0; mt < 2; ++mt)
    #pragma unroll
    for (int rr = 0; rr < 4; ++rr) {
      const int row = (t16base + mt) * 16 + lr * 4 + rr;
      #pragma unroll
      for (int bn = 0; bn < 2; ++bn) {
        const int col = (wn * 2 + bn) * 16 + lc;
        Qb[(size_t)row * 128 + col] = f2bf(acc[mt][bn][rr] + qzero[col]);
      }
    }
}

// ---------------- kAtt: per-row 2-head attention over 10 neighbors -> aggb (bf16) ----------------
__global__ __launch_bounds__(256) void kAtt(
    const unsigned short* __restrict__ Qb, const unsigned short* __restrict__ KVb,
    unsigned short* __restrict__ aggb)
{
  const int w = threadIdx.x >> 6, l = threadIdx.x & 63;
  const int i = blockIdx.x * 4 + w;
  const float q0 = bf2f(Qb[(size_t)i * 128 + l]);
  const float q1 = bf2f(Qb[(size_t)i * 128 + 64 + l]);
  const unsigned short* base = KVb + (size_t)i * K_ * 256;

  float s0[K_], s1[K_], v0[K_], v1[K_];
  #pragma unroll
  for (int kk = 0; kk < K_; ++kk) {
    const unsigned short* rp = base + kk * 256;
    const float k0 = bf2f(rp[l]);
    const float k1 = bf2f(rp[64 + l]);
    v0[kk] = bf2f(rp[128 + l]);
    v1[kk] = bf2f(rp[192 + l]);
    float p0 = q0 * k0, p1 = q1 * k1;
    #pragma unroll
    for (int t = 32; t; t >>= 1) { p0 += __shfl_xor(p0, t); p1 += __shfl_xor(p1, t); }
    s0[kk] = p0; s1[kk] = p1;
  }
  float m0 = s0[0], m1 = s1[0];
  #pragma unroll
  for (int kk = 1; kk < K_; ++kk) { m0 = fmaxf(m0, s0[kk]); m1 = fmaxf(m1, s1[kk]); }
  float sum0 = 0.f, sum1 = 0.f, a0 = 0.f, a1 = 0.f;
  #pragma unroll
  for (int kk = 0; kk < K_; ++kk) {
    const float e0 = __expf(s0[kk] - m0);
    const float e1 = __expf(s1[kk] - m1);
    sum0 += e0; sum1 += e1;
    a0 += e0 * v0[kk]; a1 += e1 * v1[kk];
  }
  aggb[(size_t)i * 128 + l]      = f2bf(__fdividef(a0, sum0));
  aggb[(size_t)i * 128 + 64 + l] = f2bf(__fdividef(a1, sum1));
}

// ---------------- kO_ln: out-proj + ReLU + LayerNorm fused -> emb (fp32) ----------------
__global__ __launch_bounds__(512) void kO_ln(
    const unsigned short* __restrict__ hb, const unsigned short* __restrict__ aggb,
    const unsigned short* __restrict__ WoB, const float* __restrict__ bo,
    const float* __restrict__ ln_g, const float* __restrict__ ln_b,
    float* __restrict__ emb)
{
  __shared__ float ps[64][4], pq[64][4];
  const int w = threadIdx.x >> 6, l = threadIdx.x & 63;
  const int wm = w >> 2, wn = w & 3;
  const int lr = l >> 4, lc = l & 15;
  const int t16base = blockIdx.x * 4 + wm * 2;
  const unsigned short* Ah0 = hb   + (size_t)(t16base * 16 + lc) * 128 + lr * 8;
  const unsigned short* Ah1 = Ah0 + 16 * 128;
  const unsigned short* Ag0 = aggb + (size_t)(t16base * 16 + lc) * 128 + lr * 8;
  const unsigned short* Ag1 = Ag0 + 16 * 128;

  f32x4 acc[2][2];
  #pragma unroll
  for (int m = 0; m < 2; ++m)
    #pragma unroll
    for (int bn = 0; bn < 2; ++bn) acc[m][bn] = (f32x4){0.f, 0.f, 0.f, 0.f};

  #pragma unroll
  for (int kt = 0; kt < 8; ++kt) {
    const bf16x8 a0 = (kt < 4) ? *(const bf16x8*)(Ah0 + kt * 32)
                               : *(const bf16x8*)(Ag0 + (kt - 4) * 32);
    const bf16x8 a1 = (kt < 4) ? *(const bf16x8*)(Ah1 + kt * 32)
                               : *(const bf16x8*)(Ag1 + (kt - 4) * 32);
    #pragma unroll
    for (int bn = 0; bn < 2; ++bn) {
      const bf16x8 b = *(const bf16x8*)(WoB + ((size_t)(kt * 8 + wn * 2 + bn) * 64 + l) * 8);
      acc[0][bn] = MFMA16(a0, b, acc[0][bn]);
      acc[1][bn] = MFMA16(a1, b, acc[1][bn]);
    }
  }

  const int c0 = (wn * 2) * 16 + lc, c1 = c0 + 16;
  const float b0v = bo[c0], b1v = bo[c1];
  float xv0[2][4], xv1[2][4];
  #pragma unroll
  for (int mt = 0; mt < 2; ++mt)
    #pragma unroll
    for (int rr = 0; rr < 4; ++rr) {
      const float x0 = fmaxf(acc[mt][0][rr] + b0v, 0.f);
      const float x1 = fmaxf(acc[mt][1][rr] + b1v, 0.f);
      xv0[mt][rr] = x0; xv1[mt][rr] = x1;
      float s = x0 + x1, q = x0 * x0 + x1 * x1;
      #pragma unroll
      for (int t = 8; t; t >>= 1) { s += __shfl_xor(s, t); q += __shfl_xor(q, t); }
      const int rloc = (wm * 2 + mt) * 16 + lr * 4 + rr;
      if (lc == 0) { ps[rloc][wn] = s; pq[rloc][wn] = q; }
    }
  __syncthreads();
  const float g0 = ln_g[c0], g1 = ln_g[c1], lb0 = ln_b[c0], lb1 = ln_b[c1];
  #pragma unroll
  for (int mt = 0; mt < 2; ++mt)
    #pragma unroll
    for (int rr = 0; rr < 4; ++rr) {
      const int rloc = (wm * 2 + mt) * 16 + lr * 4 + rr;
      const int row  = blockIdx.x * 64 + rloc;
      const float sum = ps[rloc][0] + ps[rloc][1] + ps[rloc][2] + ps[rloc][3];
      const float sq  = pq[rloc][0] + pq[rloc][1] + pq[rloc][2] + pq[rloc][3];
      const float mu  = sum * (1.0f / 128.0f);
      const float var = sq * (1.0f / 128.0f) - mu * mu;
      const float rs  = rsqrtf(var + 1e-5f);
      emb[(size_t)row * 128 + c0] = g0 * (xv0[mt][rr] - mu) * rs + lb0;
      emb[(size_t)row * 128 + c1] = g1 * (xv1[mt][rr] - mu) * rs + lb1;
    }
}

// ---------------- k3: edge predictor -> out[B][2] ----------------
__global__ __launch_bounds__(128) void k3_ep(
    const float* __restrict__ emb, const float4* __restrict__ SwP,
    const float4* __restrict__ DwP, const float* __restrict__ ep_sb,
    const float* __restrict__ ep_db, const float* __restrict__ ep_ow,
    const float* __restrict__ ep_ob, float* __restrict__ out)
{
  __shared__ float se[128], de[128], ne[128];
  __shared__ float redp[2], redn[2];
  const int c = threadIdx.x;
  const int i = blockIdx.x;
  se[c] = emb[(size_t)i * 128 + c];
  de[c] = emb[(size_t)(B_ + i) * 128 + c];
  ne[c] = emb[(size_t)(2 * B_ + i) * 128 + c];
  __syncthreads();
  float sacc = ep_sb[c], dacc = ep_db[c], nacc = ep_db[c];
  for (int k4 = 0; k4 < 32; ++k4) {
    const float4 sw = SwP[k4 * 128 + c];
    const float4 dw = DwP[k4 * 128 + c];
    sacc = dot4(((const float4*)se)[k4], sw, sacc);
    dacc = dot4(((const float4*)de)[k4], dw, dacc);
    nacc = dot4(((const float4*)ne)[k4], dw, nacc);
  }
  const float ow = ep_ow[c];
  float pp = fmaxf(sacc + dacc, 0.f) * ow;
  float pn = fmaxf(sacc + nacc, 0.f) * ow;
  for (int t = 32; t; t >>= 1) { pp += __shfl_xor(pp, t); pn += __shfl_xor(pn, t); }
  if ((c & 63) == 0) { redp[c >> 6] = pp; redn[c >> 6] = pn; }
  __syncthreads();
  if (c == 0) {
    const float ob = ep_ob[0];
    out[i * 2]     = redp[0] + redp[1] + ob;
    out[i * 2 + 1] = redn[0] + redn[1] + ob;
  }
}

// ---------------- launch ----------------
extern "C" void kernel_launch(void* const* d_in, const int* in_sizes, int n_in,
                              void* d_out, int out_size, void* d_ws, size_t ws_size,
                              hipStream_t stream) {
  const int*   nodes     = (const int*)d_in[0];
  const int*   eids      = (const int*)d_in[1];
  const float* dt_nbr    = (const float*)d_in[2];
  const float* nfeat     = (const float*)d_in[3];
  const float* mem_data  = (const float*)d_in[4];
  const float* mem_time  = (const float*)d_in[5];
  const float* mail_data = (const float*)d_in[6];
  const float* mail_time = (const float*)d_in[7];
  const float* efeat     = (const float*)d_in[8];
  const float* time_w    = (const float*)d_in[9];
  const float* time_b    = (const float*)d_in[10];
  const float* gru_w_ih  = (const float*)d_in[11];
  const float* gru_w_hh  = (const float*)d_in[12];
  const float* gru_b_ih  = (const float*)d_in[13];
  const float* gru_b_hh  = (const float*)d_in[14];
  const float* wq        = (const float*)d_in[15];
  const float* bq        = (const float*)d_in[16];
  const float* wk        = (const float*)d_in[17];
  const float* bk        = (const float*)d_in[18];
  const float* wv        = (const float*)d_in[19];
  const float* bv        = (const float*)d_in[20];
  const float* wo        = (const float*)d_in[21];
  const float* bo        = (const float*)d_in[22];
  const float* ln_g      = (const float*)d_in[23];
  const float* ln_b      = (const float*)d_in[24];
  const float* ep_sw     = (const float*)d_in[25];
  const float* ep_sb     = (const float*)d_in[26];
  const float* ep_dw     = (const float*)d_in[27];
  const float* ep_db     = (const float*)d_in[28];
  const float* ep_ow     = (const float*)d_in[29];
  const float* ep_ob     = (const float*)d_in[30];
  float* out = (float*)d_out;
  float* ws  = (float*)d_ws;

  unsigned short* Qb    = (unsigned short*)(ws + OFF_QB);
  unsigned short* aggb  = (unsigned short*)(ws + OFF_AGG);
  unsigned short* hb    = (unsigned short*)(ws + OFF_HB);
  unsigned short* KVb   = (unsigned short*)(ws + OFF_KVB);
  float*          emb   = ws + OFF_EMB;
  unsigned short* WcatP = (unsigned short*)(ws + OFF_WCAT);
  unsigned short* WkvP  = (unsigned short*)(ws + OFF_WKV);
  float*          bcat  = ws + OFF_BCAT;
  float*          bkv   = ws + OFF_BKV;
  unsigned short* WqB   = (unsigned short*)(ws + OFF_WQB);
  unsigned short* WoB   = (unsigned short*)(ws + OFF_WOB);
  float4*         SwP   = (float4*)(ws + OFF_SWP);
  float4*         DwP   = (float4*)(ws + OFF_DWP);
  float*          qzero = ws + OFF_QZ;

  k0_all<<<1892, 256, 0, stream>>>(gru_w_ih, gru_w_hh, wk, wv, wq, wo, ep_sw, ep_dw,
                                   gru_b_ih, gru_b_hh, bk, bv, time_b, bq,
                                   WcatP, WkvP, WqB, WoB, SwP, DwP, bcat, bkv, qzero);
  k1_fused<<<NTOT / 32, 512, 0, stream>>>(nodes, mail_data, mem_data, mail_time,
                                          mem_time, time_w, time_b, WcatP, bcat,
                                          nfeat, hb);
  k2_fused<<<RKV / 32, 512, 0, stream>>>(hb, eids, dt_nbr, efeat, time_w, time_b,
                                         WkvP, bkv, KVb);
  kQ_gemm<<<ND_ / 64, 512, 0, stream>>>(hb, WqB, qzero, Qb);
  kAtt<<<ND_ / 4, 256, 0, stream>>>(Qb, KVb, aggb);
  kO_ln<<<ND_ / 64, 512, 0, stream>>>(hb, aggb, WoB, bo, ln_g, ln_b, emb);
  k3_ep<<<B_, 128, 0, stream>>>(emb, SwP, DwP, ep_sb, ep_db, ep_ow, ep_ob, out);
}

// Round 16
// 377.988 us; speedup vs baseline: 1.1327x; 1.0082x over previous
//
#include <hip/hip_runtime.h>

// ---------------- problem constants ----------------
constexpr int ND_   = 12288;           // 3*B
constexpr int K_    = 10;
constexpr int NTOT  = ND_ * (1 + K_);  // 135168
constexpr int B_    = 4096;
constexpr int RKV   = ND_ * K_;        // 122880

// ---------------- ws layout (float offsets) ----------------
constexpr size_t OFF_QB   = 0;          // ushort[ND_*128]
constexpr size_t OFF_AGG  = 786432;     // ushort[ND_*128]
constexpr size_t OFF_HB   = 43253760;   // ushort[NTOT*128] -> 8,650,752 fl
constexpr size_t OFF_KVB  = 51904512;   // ushort[RKV*256]  -> 15,728,640 fl
constexpr size_t OFF_EMB  = 67633152;   // float[ND_*128]   -> 1,572,864
constexpr size_t OFF_WCAT = 69206016;   // ushort[640*512]  -> 163,840 fl
constexpr size_t OFF_WKV  = 69369856;   // ushort[384*256]  -> 49,152 fl
constexpr size_t OFF_BCAT = 69419008;   // float[512]
constexpr size_t OFF_BKV  = 69419520;   // float[256]
constexpr size_t OFF_WQB  = 69419776;   // ushort[128*128]
constexpr size_t OFF_WOB  = 69427968;   // ushort[256*128]
constexpr size_t OFF_SWP  = 69444352;   // float4[32*128]
constexpr size_t OFF_DWP  = 69460736;   // float4[32*128]
constexpr size_t OFF_QZ   = 69477120;   // float[128]

#define DEVFN __device__ __forceinline__

typedef __attribute__((ext_vector_type(8))) short bf16x8;
typedef __attribute__((ext_vector_type(4))) float f32x4;
#define MFMA16(a, b, c) __builtin_amdgcn_mfma_f32_16x16x32_bf16((a), (b), (c), 0, 0, 0)

DEVFN unsigned short f2bf(float x) {           // RNE float->bf16 (scalar path)
  unsigned int u = __float_as_uint(x);
  u = (u + 0x7FFFu + ((u >> 16) & 1u)) >> 16;
  return (unsigned short)u;
}
DEVFN float bf2f(unsigned short h) { return __uint_as_float(((unsigned int)h) << 16); }

// packed RNE f32->bf16 via HW cvt
DEVFN bf16x8 packcvt(float4 a, float4 b) {
  union { unsigned int u[4]; bf16x8 v; } r;
  asm("v_cvt_pk_bf16_f32 %0, %1, %2" : "=v"(r.u[0]) : "v"(a.x), "v"(a.y));
  asm("v_cvt_pk_bf16_f32 %0, %1, %2" : "=v"(r.u[1]) : "v"(a.z), "v"(a.w));
  asm("v_cvt_pk_bf16_f32 %0, %1, %2" : "=v"(r.u[2]) : "v"(b.x), "v"(b.y));
  asm("v_cvt_pk_bf16_f32 %0, %1, %2" : "=v"(r.u[3]) : "v"(b.z), "v"(b.w));
  return r.v;
}

DEVFN float dot4(const float4 a, const float4 b, float acc) {
  acc = fmaf(a.x, b.x, acc);
  acc = fmaf(a.y, b.y, acc);
  acc = fmaf(a.z, b.z, acc);
  acc = fmaf(a.w, b.w, acc);
  return acc;
}
// fast transcendentals (error ~1e-6 rel, << bf16 quantization)
DEVFN float fsig(float x)  { return __fdividef(1.0f, 1.0f + __expf(-x)); }
DEVFN float ftanh(float x) {
  x = fminf(fmaxf(x, -15.0f), 15.0f);
  const float t = __expf(2.0f * x);
  return __fdividef(t - 1.0f, t + 1.0f);
}

// ---------------- k0_all: all weight/bias packs in one launch ----------------
// Wcat c'-mapping: c' = q*128 + jb*64 + g*16 + t, channel j = q*32 + jb*16 + t, g in {R,Z,Ni,Nh}.
// k<512: w_ih (R/Z/Ni; zero Nh); k>=512: w_hh (R/Z/Nh; zero Ni).
__global__ void k0_all(const float* __restrict__ w_ih, const float* __restrict__ w_hh,
                       const float* __restrict__ wk,   const float* __restrict__ wv,
                       const float* __restrict__ wq,   const float* __restrict__ wo,
                       const float* __restrict__ sw,   const float* __restrict__ dwm,
                       const float* __restrict__ b_ih, const float* __restrict__ b_hh,
                       const float* __restrict__ bk,   const float* __restrict__ bv,
                       const float* __restrict__ time_b, const float* __restrict__ bq,
                       unsigned short* __restrict__ WcatP, unsigned short* __restrict__ WkvP,
                       unsigned short* __restrict__ WqB,   unsigned short* __restrict__ WoB,
                       float4* __restrict__ SwP, float4* __restrict__ DwP,
                       float* __restrict__ bcat, float* __restrict__ bkv,
                       float* __restrict__ qzero)
{
  int gid = blockIdx.x * 256 + threadIdx.x;
  if (gid < 327680) {                    // WcatP: 20 kt x 32 nt
    int f = gid >> 9, idx = gid & 511;
    int l = idx >> 3, j8 = idx & 7;
    int kt = f >> 5, nt = f & 31;
    int k = kt * 32 + (l >> 4) * 8 + j8;
    int c = nt * 16 + (l & 15);
    int q = c >> 7, jb = (c >> 6) & 1, g = (c >> 4) & 3, j = q * 32 + jb * 16 + (c & 15);
    float w;
    if (g == 0)      w = (k < 512) ? w_ih[(size_t)j * 512 + k]         : w_hh[(size_t)j * 128 + (k - 512)];
    else if (g == 1) w = (k < 512) ? w_ih[(size_t)(128 + j) * 512 + k] : w_hh[(size_t)(128 + j) * 128 + (k - 512)];
    else if (g == 2) w = (k < 512) ? w_ih[(size_t)(256 + j) * 512 + k] : 0.0f;
    else             w = (k < 512) ? 0.0f : w_hh[(size_t)(256 + j) * 128 + (k - 512)];
    WcatP[gid] = f2bf(w);
    return;
  }
  gid -= 327680;
  if (gid < 98304) {                     // WkvP: 12 kt x 16 nt (K|V)
    int f = gid >> 9, idx = gid & 511;
    int l = idx >> 3, j8 = idx & 7;
    int kt = f >> 4, nt = f & 15;
    int k = kt * 32 + (l >> 4) * 8 + j8;
    int c = nt * 16 + (l & 15);
    float w = (c < 128) ? wk[(size_t)c * 384 + k] : wv[(size_t)(c - 128) * 384 + k];
    WkvP[gid] = f2bf(w);
    return;
  }
  gid -= 98304;
  if (gid < 49152) {                     // WqB (4x8) then WoB (8x8)
    if (gid < 16384) {
      int f = gid >> 9, idx = gid & 511;
      int l = idx >> 3, j8 = idx & 7;
      int kt = f >> 3, nt = f & 7;
      int k = kt * 32 + (l >> 4) * 8 + j8;
      int c = nt * 16 + (l & 15);
      WqB[gid] = f2bf(wq[(size_t)c * 256 + k]);
    } else {
      int g2 = gid - 16384;
      int f = g2 >> 9, idx = g2 & 511;
      int l = idx >> 3, j8 = idx & 7;
      int kt = f >> 3, nt = f & 7;
      int k = kt * 32 + (l >> 4) * 8 + j8;
      int c = nt * 16 + (l & 15);
      WoB[g2] = f2bf(wo[(size_t)c * 256 + k]);
    }
    return;
  }
  gid -= 49152;
  if (gid < 8960) {                      // SwP / DwP / bcat / bkv
    if (gid < 4096) {
      int k4 = gid / 128, c = gid % 128;
      const float* s = sw + c * 128 + 4 * k4;
      SwP[gid] = make_float4(s[0], s[1], s[2], s[3]);
    } else if (gid < 8192) {
      int id = gid - 4096;
      int k4 = id / 128, c = id % 128;
      const float* s = dwm + c * 128 + 4 * k4;
      DwP[id] = make_float4(s[0], s[1], s[2], s[3]);
    } else if (gid < 8704) {
      int id = gid - 8192;
      int q = id >> 7, jb = (id >> 6) & 1, g = (id >> 4) & 3, lcc = id & 15;
      int j = q * 32 + jb * 16 + lcc;
      float b;
      if (g == 0)      b = b_ih[j] + b_hh[j];
      else if (g == 1) b = b_ih[128 + j] + b_hh[128 + j];
      else if (g == 2) b = b_ih[256 + j];
      else             b = b_hh[256 + j];
      bcat[id] = b;
    } else {
      int id = gid - 8704;
      bkv[id] = (id < 128) ? bk[id] : bv[id - 128];
    }
    return;
  }
  gid -= 8960;
  if (gid < 128) {                       // qzero (accurate cos, one-off)
    float acc = bq[gid];
    for (int k = 0; k < 128; ++k)
      acc = fmaf(cosf(time_b[k]), wq[gid * 256 + 128 + k], acc);
    qzero[gid] = acc;
  }
}

// ---------------- k1_fused: coalesced chunk-pipelined MFMA GRU ----------------
// 32 rows/block, 512 thr. K split into 5 chunks x 4 kt (8KB each), ping-pong 2x8KB.
// STAGE per chunk: thread (r=t>>4, j=t&15) reads 32B CONTIGUOUS of its row (cols
// c*128+j*8) -> 512B burst per row (R15's coalescing). kt-row swizzle (r15+kt)&15
// on write+read (R15-proven). Pipeline: gather(c+1) early -> MFMA(c) -> write late
// -> barrier (R12 structure). At c=4 the gather slot issues nfeat loads instead.
__global__ __launch_bounds__(512, 4) void k1_fused(
    const int* __restrict__ nodes, const float* __restrict__ mail_data,
    const float* __restrict__ mem_data, const float* __restrict__ mail_time,
    const float* __restrict__ mem_time, const float* __restrict__ time_w,
    const float* __restrict__ time_b, const unsigned short* __restrict__ WcatP,
    const float* __restrict__ bcat, const float* __restrict__ nfeat,
    unsigned short* __restrict__ hb)
{
  __shared__ unsigned short As[2][4 * 1024];   // 2 bufs x 8KB
  __shared__ float nf[32][132];                // 16.9KB nfeat stage
  const int tid = threadIdx.x;
  const int rbase = blockIdx.x * 32;

  const int r = tid >> 4, j = tid & 15;
  const int half = r >> 4, r15 = r & 15;
  const int n = nodes[rbase + r];
  const float drow = mail_time[n] - mem_time[n];
  const float* mailp = mail_data + (size_t)n * 384;
  const float* memp  = mem_data  + (size_t)n * 128;

  const int ktg0 = j >> 2, q = j & 3;          // chunk-local kt and quarter for this lane

  // gather chunk c's 8 floats for this lane (cols c*128 + j*8)
  auto gather = [&](int c, float4& v0, float4& v1) {
    if (c < 3) {
      const float* s = mailp + c * 128 + j * 8;
      v0 = *(const float4*)s; v1 = *(const float4*)(s + 4);
    } else if (c == 4) {
      const float* s = memp + j * 8;
      v0 = *(const float4*)s; v1 = *(const float4*)(s + 4);
    } else {                               // tenc, k = j*8..+8
      const float4 w0 = *(const float4*)(time_w + j * 8);
      const float4 w1 = *(const float4*)(time_w + j * 8 + 4);
      const float4 b0 = *(const float4*)(time_b + j * 8);
      const float4 b1 = *(const float4*)(time_b + j * 8 + 4);
      v0.x = __cosf(fmaf(drow, w0.x, b0.x)); v0.y = __cosf(fmaf(drow, w0.y, b0.y));
      v0.z = __cosf(fmaf(drow, w0.z, b0.z)); v0.w = __cosf(fmaf(drow, w0.w, b0.w));
      v1.x = __cosf(fmaf(drow, w1.x, b1.x)); v1.y = __cosf(fmaf(drow, w1.y, b1.y));
      v1.z = __cosf(fmaf(drow, w1.z, b1.z)); v1.w = __cosf(fmaf(drow, w1.w, b1.w));
    }
  };
  // write lane's bf16x8 into buf b at chunk c (kt = c*4 + ktg0, swizzled row)
  auto wstage = [&](int b, int c, float4 v0, float4 v1) {
    const int kt = c * 4 + ktg0;
    const int rowp = (r15 + kt) & 15;
    unsigned short* wb = &As[b][(size_t)ktg0 * 1024 + (size_t)(half * 64 + q * 16 + rowp) * 8];
    *(bf16x8*)wb = packcvt(v0, v1);
  };

  // ---- prologue: stage chunk 0 into buf 0 ----
  {
    float4 v0, v1;
    gather(0, v0, v1);
    wstage(0, 0, v0, v1);
  }
  __syncthreads();

  // ---- MFMA identities ----
  const int w = tid >> 6, l = tid & 63;
  const int lr = l >> 4, lc = l & 15;
  const unsigned short* Bp = WcatP + (size_t)(w * 4) * 512 + l * 8;

  f32x4 acc[2][4];
  #pragma unroll
  for (int m = 0; m < 2; ++m)
    #pragma unroll
    for (int bn = 0; bn < 4; ++bn) acc[m][bn] = (f32x4){0.f, 0.f, 0.f, 0.f};

  float4 nfv0, nfv1;                       // nfeat landing regs (issued at c==4)
  #pragma unroll
  for (int c = 0; c < 5; ++c) {
    float4 nv0, nv1;
    if (c < 4) gather(c + 1, nv0, nv1);    // issue next-chunk loads early
    else {                                 // issue nfeat loads under last MFMA chunk
      const float* np = nfeat + (size_t)n * 128 + j * 8;
      nfv0 = *(const float4*)np; nfv1 = *(const float4*)(np + 4);
    }
    #pragma unroll
    for (int ktl = 0; ktl < 4; ++ktl) {
      const int kt = c * 4 + ktl;
      const int rowp = (lc + kt) & 15;
      const unsigned short* Ab = &As[c & 1][(size_t)ktl * 1024 + (size_t)(lr * 16 + rowp) * 8];
      const bf16x8 A0 = *(const bf16x8*)Ab;
      const bf16x8 A1 = *(const bf16x8*)(Ab + 512);
      #pragma unroll
      for (int bn = 0; bn < 4; ++bn) {
        const bf16x8 Bf = *(const bf16x8*)(Bp + ((size_t)kt * 32 + bn) * 512);
        acc[0][bn] = MFMA16(A0, Bf, acc[0][bn]);
        acc[1][bn] = MFMA16(A1, Bf, acc[1][bn]);
      }
    }
    if (c < 4) {
      wstage((c + 1) & 1, c + 1, nv0, nv1);   // write-late into ping-pong buf
      __syncthreads();
    }
  }

  // ---- stage nfeat (already in regs) ----
  *(float4*)(&nf[r][j * 8])     = nfv0;
  *(float4*)(&nf[r][j * 8 + 4]) = nfv1;
  __syncthreads();

  // ---- GRU epilogue: mem from buf[0] (chunk 4 = kt 16..19), nfeat from LDS ----
  const int jcol = (w >> 1) * 32 + (w & 1) * 16 + lc;
  float bg[4];
  #pragma unroll
  for (int g = 0; g < 4; ++g) bg[g] = bcat[w * 64 + g * 16 + lc];
  const int memktl = w >> 1;               // kt = 16 + (w>>1)
  const int qp = (w & 1) * 2 + (lc >> 3);
  const int el = lc & 7;

  #pragma unroll
  for (int mt = 0; mt < 2; ++mt) {
    #pragma unroll
    for (int rr = 0; rr < 4; ++rr) {
      const int rloc = mt * 16 + lr * 4 + rr;
      const int grow = rbase + rloc;
      const int rowp = ((rloc & 15) + 16 + memktl) & 15;
      const float aR  = acc[mt][0][rr] + bg[0];
      const float aZ  = acc[mt][1][rr] + bg[1];
      const float aNi = acc[mt][2][rr] + bg[2];
      const float aNh = acc[mt][3][rr] + bg[3];
      const float r_  = fsig(aR);
      const float z_  = fsig(aZ);
      const float n_  = ftanh(aNi + r_ * aNh);
      const float mem = bf2f(As[0][(size_t)memktl * 1024 +
                                   (size_t)(mt * 64 + qp * 16 + rowp) * 8 + el]);
      const float h = nf[rloc][jcol] + (1.0f - z_) * n_ + z_ * mem;
      hb[(size_t)grow * 128 + jcol] = f2bf(h);
    }
  }
}

// ---------------- k2_fused: gather + KV projection, 1 m-tile/wave ----------------
DEVFN void k2s(const unsigned short* __restrict__ WkvP, int kt, int wn, int l,
               bf16x8 a, f32x4 (&acc)[4]) {
  #pragma unroll
  for (int bn = 0; bn < 4; ++bn) {
    const bf16x8 b = *(const bf16x8*)(WkvP + ((size_t)(kt * 16 + wn * 4 + bn) * 64 + l) * 8);
    acc[bn] = MFMA16(a, b, acc[bn]);
  }
}

__global__ __launch_bounds__(512) void k2_fused(
    const unsigned short* __restrict__ hb, const int* __restrict__ eids,
    const float* __restrict__ dt_nbr, const float* __restrict__ efeat,
    const float* __restrict__ time_w, const float* __restrict__ time_b,
    const unsigned short* __restrict__ WkvP, const float* __restrict__ bkv,
    unsigned short* __restrict__ KVb)
{
  const int w = threadIdx.x >> 6, l = threadIdx.x & 63;
  const int wm = w >> 2, wn = w & 3;           // 2 m-groups x 4 n-groups
  const int lr = l >> 4, lc = l & 15;
  const int t16 = blockIdx.x * 2 + wm;
  const int rbase = t16 * 16;

  int eld = 0; float dld = 0.f;
  if (l < 16) { eld = eids[rbase + l]; dld = dt_nbr[rbase + l]; }
  const int   eid = __shfl(eld, lc);
  const float dt  = __shfl(dld, lc);

  const float* ep = efeat + (size_t)eid * 128 + lr * 8;
  bf16x8 ea[4];
  #pragma unroll
  for (int qq = 0; qq < 4; ++qq)
    ea[qq] = packcvt(((const float4*)(ep + qq * 32))[0], ((const float4*)(ep + qq * 32))[1]);
  const unsigned short* hp = hb + (size_t)(ND_ + rbase + lc) * 128 + lr * 8;
  bf16x8 hh[4];
  #pragma unroll
  for (int qq = 0; qq < 4; ++qq) hh[qq] = *(const bf16x8*)(hp + qq * 32);
  bf16x8 tt[4];
  #pragma unroll
  for (int qq = 0; qq < 4; ++qq) {
    const int c0 = qq * 32 + lr * 8;
    const float4 w0 = ((const float4*)(time_w + c0))[0];
    const float4 w1 = ((const float4*)(time_w + c0))[1];
    const float4 b0 = ((const float4*)(time_b + c0))[0];
    const float4 b1 = ((const float4*)(time_b + c0))[1];
    float4 u, v;
    u.x = __cosf(fmaf(dt, w0.x, b0.x)); u.y = __cosf(fmaf(dt, w0.y, b0.y));
    u.z = __cosf(fmaf(dt, w0.z, b0.z)); u.w = __cosf(fmaf(dt, w0.w, b0.w));
    v.x = __cosf(fmaf(dt, w1.x, b1.x)); v.y = __cosf(fmaf(dt, w1.y, b1.y));
    v.z = __cosf(fmaf(dt, w1.z, b1.z)); v.w = __cosf(fmaf(dt, w1.w, b1.w));
    tt[qq] = packcvt(u, v);
  }

  f32x4 acc[4];
  #pragma unroll
  for (int bn = 0; bn < 4; ++bn) acc[bn] = (f32x4){0.f, 0.f, 0.f, 0.f};

  #pragma unroll
  for (int qq = 0; qq < 4; ++qq) k2s(WkvP, qq, wn, l, hh[qq], acc);
  #pragma unroll
  for (int qq = 0; qq < 4; ++qq) k2s(WkvP, 4 + qq, wn, l, ea[qq], acc);
  #pragma unroll
  for (int qq = 0; qq < 4; ++qq) k2s(WkvP, 8 + qq, wn, l, tt[qq], acc);

  float bb[4];
  #pragma unroll
  for (int bn = 0; bn < 4; ++bn) bb[bn] = bkv[wn * 64 + bn * 16 + lc];

  #pragma unroll
  for (int rr = 0; rr < 4; ++rr) {
    const size_t grow = (size_t)(rbase + lr * 4 + rr);
    #pragma unroll
    for (int bn = 0; bn < 4; ++bn)
      KVb[grow * 256 + wn * 64 + bn * 16 + lc] = f2bf(acc[bn][rr] + bb[bn]);
  }
}

// ---------------- kQ_gemm: Q = dst_h @ wq[:, :128]^T + qzero -> Qb (bf16) ----------------
__global__ __launch_bounds__(512) void kQ_gemm(
    const unsigned short* __restrict__ hb, const unsigned short* __restrict__ WqB,
    const float* __restrict__ qzero, unsigned short* __restrict__ Qb)
{
  const int w = threadIdx.x >> 6, l = threadIdx.x & 63;
  const int wm = w >> 2, wn = w & 3;
  const int lr = l >> 4, lc = l & 15;
  const int t16base = blockIdx.x * 4 + wm * 2;
  const unsigned short* Ar0 = hb + (size_t)(t16base * 16 + lc) * 128 + lr * 8;
  const unsigned short* Ar1 = Ar0 + 16 * 128;

  f32x4 acc[2][2];
  #pragma unroll
  for (int m = 0; m < 2; ++m)
    #pragma unroll
    for (int bn = 0; bn < 2; ++bn) acc[m][bn] = (f32x4){0.f, 0.f, 0.f, 0.f};

  #pragma unroll
  for (int kt = 0; kt < 4; ++kt) {
    const bf16x8 a0 = *(const bf16x8*)(Ar0 + kt * 32);
    const bf16x8 a1 = *(const bf16x8*)(Ar1 + kt * 32);
    #pragma unroll
    for (int bn = 0; bn < 2; ++bn) {
      const bf16x8 b = *(const bf16x8*)(WqB + ((size_t)(kt * 8 + wn * 2 + bn) * 64 + l) * 8);
      acc[0][bn] = MFMA16(a0, b, acc[0][bn]);
      acc[1][bn] = MFMA16(a1, b, acc[1][bn]);
    }
  }

  #pragma unroll
  for (int mt = 0; mt < 2; ++mt)
    #pragma unroll
    for (int rr = 0; rr < 4; ++rr) {
      const int row = (t16base + mt) * 16 + lr * 4 + rr;
      #pragma unroll
      for (int bn = 0; bn < 2; ++bn) {
        const int col = (wn * 2 + bn) * 16 + lc;
        Qb[(size_t)row * 128 + col] = f2bf(acc[mt][bn][rr] + qzero[col]);
      }
    }
}

// ---------------- kAtt: per-row 2-head attention over 10 neighbors -> aggb (bf16) ----------------
__global__ __launch_bounds__(256) void kAtt(
    const unsigned short* __restrict__ Qb, const unsigned short* __restrict__ KVb,
    unsigned short* __restrict__ aggb)
{
  const int w = threadIdx.x >> 6, l = threadIdx.x & 63;
  const int i = blockIdx.x * 4 + w;
  const float q0 = bf2f(Qb[(size_t)i * 128 + l]);
  const float q1 = bf2f(Qb[(size_t)i * 128 + 64 + l]);
  const unsigned short* base = KVb + (size_t)i * K_ * 256;

  float s0[K_], s1[K_], v0[K_], v1[K_];
  #pragma unroll
  for (int kk = 0; kk < K_; ++kk) {
    const unsigned short* rp = base + kk * 256;
    const float k0 = bf2f(rp[l]);
    const float k1 = bf2f(rp[64 + l]);
    v0[kk] = bf2f(rp[128 + l]);
    v1[kk] = bf2f(rp[192 + l]);
    float p0 = q0 * k0, p1 = q1 * k1;
    #pragma unroll
    for (int t = 32; t; t >>= 1) { p0 += __shfl_xor(p0, t); p1 += __shfl_xor(p1, t); }
    s0[kk] = p0; s1[kk] = p1;
  }
  float m0 = s0[0], m1 = s1[0];
  #pragma unroll
  for (int kk = 1; kk < K_; ++kk) { m0 = fmaxf(m0, s0[kk]); m1 = fmaxf(m1, s1[kk]); }
  float sum0 = 0.f, sum1 = 0.f, a0 = 0.f, a1 = 0.f;
  #pragma unroll
  for (int kk = 0; kk < K_; ++kk) {
    const float e0 = __expf(s0[kk] - m0);
    const float e1 = __expf(s1[kk] - m1);
    sum0 += e0; sum1 += e1;
    a0 += e0 * v0[kk]; a1 += e1 * v1[kk];
  }
  aggb[(size_t)i * 128 + l]      = f2bf(__fdividef(a0, sum0));
  aggb[(size_t)i * 128 + 64 + l] = f2bf(__fdividef(a1, sum1));
}

// ---------------- kO_ln: out-proj + ReLU + LayerNorm fused -> emb (fp32) ----------------
__global__ __launch_bounds__(512) void kO_ln(
    const unsigned short* __restrict__ hb, const unsigned short* __restrict__ aggb,
    const unsigned short* __restrict__ WoB, const float* __restrict__ bo,
    const float* __restrict__ ln_g, const float* __restrict__ ln_b,
    float* __restrict__ emb)
{
  __shared__ float ps[64][4], pq[64][4];
  const int w = threadIdx.x >> 6, l = threadIdx.x & 63;
  const int wm = w >> 2, wn = w & 3;
  const int lr = l >> 4, lc = l & 15;
  const int t16base = blockIdx.x * 4 + wm * 2;
  const unsigned short* Ah0 = hb   + (size_t)(t16base * 16 + lc) * 128 + lr * 8;
  const unsigned short* Ah1 = Ah0 + 16 * 128;
  const unsigned short* Ag0 = aggb + (size_t)(t16base * 16 + lc) * 128 + lr * 8;
  const unsigned short* Ag1 = Ag0 + 16 * 128;

  f32x4 acc[2][2];
  #pragma unroll
  for (int m = 0; m < 2; ++m)
    #pragma unroll
    for (int bn = 0; bn < 2; ++bn) acc[m][bn] = (f32x4){0.f, 0.f, 0.f, 0.f};

  #pragma unroll
  for (int kt = 0; kt < 8; ++kt) {
    const bf16x8 a0 = (kt < 4) ? *(const bf16x8*)(Ah0 + kt * 32)
                               : *(const bf16x8*)(Ag0 + (kt - 4) * 32);
    const bf16x8 a1 = (kt < 4) ? *(const bf16x8*)(Ah1 + kt * 32)
                               : *(const bf16x8*)(Ag1 + (kt - 4) * 32);
    #pragma unroll
    for (int bn = 0; bn < 2; ++bn) {
      const bf16x8 b = *(const bf16x8*)(WoB + ((size_t)(kt * 8 + wn * 2 + bn) * 64 + l) * 8);
      acc[0][bn] = MFMA16(a0, b, acc[0][bn]);
      acc[1][bn] = MFMA16(a1, b, acc[1][bn]);
    }
  }

  const int c0 = (wn * 2) * 16 + lc, c1 = c0 + 16;
  const float b0v = bo[c0], b1v = bo[c1];
  float xv0[2][4], xv1[2][4];
  #pragma unroll
  for (int mt = 0; mt < 2; ++mt)
    #pragma unroll
    for (int rr = 0; rr < 4; ++rr) {
      const float x0 = fmaxf(acc[mt][0][rr] + b0v, 0.f);
      const float x1 = fmaxf(acc[mt][1][rr] + b1v, 0.f);
      xv0[mt][rr] = x0; xv1[mt][rr] = x1;
      float s = x0 + x1, q = x0 * x0 + x1 * x1;
      #pragma unroll
      for (int t = 8; t; t >>= 1) { s += __shfl_xor(s, t); q += __shfl_xor(q, t); }
      const int rloc = (wm * 2 + mt) * 16 + lr * 4 + rr;
      if (lc == 0) { ps[rloc][wn] = s; pq[rloc][wn] = q; }
    }
  __syncthreads();
  const float g0 = ln_g[c0], g1 = ln_g[c1], lb0 = ln_b[c0], lb1 = ln_b[c1];
  #pragma unroll
  for (int mt = 0; mt < 2; ++mt)
    #pragma unroll
    for (int rr = 0; rr < 4; ++rr) {
      const int rloc = (wm * 2 + mt) * 16 + lr * 4 + rr;
      const int row  = blockIdx.x * 64 + rloc;
      const float sum = ps[rloc][0] + ps[rloc][1] + ps[rloc][2] + ps[rloc][3];
      const float sq  = pq[rloc][0] + pq[rloc][1] + pq[rloc][2] + pq[rloc][3];
      const float mu  = sum * (1.0f / 128.0f);
      const float var = sq * (1.0f / 128.0f) - mu * mu;
      const float rs  = rsqrtf(var + 1e-5f);
      emb[(size_t)row * 128 + c0] = g0 * (xv0[mt][rr] - mu) * rs + lb0;
      emb[(size_t)row * 128 + c1] = g1 * (xv1[mt][rr] - mu) * rs + lb1;
    }
}

// ---------------- k3: edge predictor -> out[B][2] ----------------
__global__ __launch_bounds__(128) void k3_ep(
    const float* __restrict__ emb, const float4* __restrict__ SwP,
    const float4* __restrict__ DwP, const float* __restrict__ ep_sb,
    const float* __restrict__ ep_db, const float* __restrict__ ep_ow,
    const float* __restrict__ ep_ob, float* __restrict__ out)
{
  __shared__ float se[128], de[128], ne[128];
  __shared__ float redp[2], redn[2];
  const int c = threadIdx.x;
  const int i = blockIdx.x;
  se[c] = emb[(size_t)i * 128 + c];
  de[c] = emb[(size_t)(B_ + i) * 128 + c];
  ne[c] = emb[(size_t)(2 * B_ + i) * 128 + c];
  __syncthreads();
  float sacc = ep_sb[c], dacc = ep_db[c], nacc = ep_db[c];
  for (int k4 = 0; k4 < 32; ++k4) {
    const float4 sw = SwP[k4 * 128 + c];
    const float4 dw = DwP[k4 * 128 + c];
    sacc = dot4(((const float4*)se)[k4], sw, sacc);
    dacc = dot4(((const float4*)de)[k4], dw, dacc);
    nacc = dot4(((const float4*)ne)[k4], dw, nacc);
  }
  const float ow = ep_ow[c];
  float pp = fmaxf(sacc + dacc, 0.f) * ow;
  float pn = fmaxf(sacc + nacc, 0.f) * ow;
  for (int t = 32; t; t >>= 1) { pp += __shfl_xor(pp, t); pn += __shfl_xor(pn, t); }
  if ((c & 63) == 0) { redp[c >> 6] = pp; redn[c >> 6] = pn; }
  __syncthreads();
  if (c == 0) {
    const float ob = ep_ob[0];
    out[i * 2]     = redp[0] + redp[1] + ob;
    out[i * 2 + 1] = redn[0] + redn[1] + ob;
  }
}

// ---------------- launch ----------------
extern "C" void kernel_launch(void* const* d_in, const int* in_sizes, int n_in,
                              void* d_out, int out_size, void* d_ws, size_t ws_size,
                              hipStream_t stream) {
  const int*   nodes     = (const int*)d_in[0];
  const int*   eids      = (const int*)d_in[1];
  const float* dt_nbr    = (const float*)d_in[2];
  const float* nfeat     = (const float*)d_in[3];
  const float* mem_data  = (const float*)d_in[4];
  const float* mem_time  = (const float*)d_in[5];
  const float* mail_data = (const float*)d_in[6];
  const float* mail_time = (const float*)d_in[7];
  const float* efeat     = (const float*)d_in[8];
  const float* time_w    = (const float*)d_in[9];
  const float* time_b    = (const float*)d_in[10];
  const float* gru_w_ih  = (const float*)d_in[11];
  const float* gru_w_hh  = (const float*)d_in[12];
  const float* gru_b_ih  = (const float*)d_in[13];
  const float* gru_b_hh  = (const float*)d_in[14];
  const float* wq        = (const float*)d_in[15];
  const float* bq        = (const float*)d_in[16];
  const float* wk        = (const float*)d_in[17];
  const float* bk        = (const float*)d_in[18];
  const float* wv        = (const float*)d_in[19];
  const float* bv        = (const float*)d_in[20];
  const float* wo        = (const float*)d_in[21];
  const float* bo        = (const float*)d_in[22];
  const float* ln_g      = (const float*)d_in[23];
  const float* ln_b      = (const float*)d_in[24];
  const float* ep_sw     = (const float*)d_in[25];
  const float* ep_sb     = (const float*)d_in[26];
  const float* ep_dw     = (const float*)d_in[27];
  const float* ep_db     = (const float*)d_in[28];
  const float* ep_ow     = (const float*)d_in[29];
  const float* ep_ob     = (const float*)d_in[30];
  float* out = (float*)d_out;
  float* ws  = (float*)d_ws;

  unsigned short* Qb    = (unsigned short*)(ws + OFF_QB);
  unsigned short* aggb  = (unsigned short*)(ws + OFF_AGG);
  unsigned short* hb    = (unsigned short*)(ws + OFF_HB);
  unsigned short* KVb   = (unsigned short*)(ws + OFF_KVB);
  float*          emb   = ws + OFF_EMB;
  unsigned short* WcatP = (unsigned short*)(ws + OFF_WCAT);
  unsigned short* WkvP  = (unsigned short*)(ws + OFF_WKV);
  float*          bcat  = ws + OFF_BCAT;
  float*          bkv   = ws + OFF_BKV;
  unsigned short* WqB   = (unsigned short*)(ws + OFF_WQB);
  unsigned short* WoB   = (unsigned short*)(ws + OFF_WOB);
  float4*         SwP   = (float4*)(ws + OFF_SWP);
  float4*         DwP   = (float4*)(ws + OFF_DWP);
  float*          qzero = ws + OFF_QZ;

  k0_all<<<1892, 256, 0, stream>>>(gru_w_ih, gru_w_hh, wk, wv, wq, wo, ep_sw, ep_dw,
                                   gru_b_ih, gru_b_hh, bk, bv, time_b, bq,
                                   WcatP, WkvP, WqB, WoB, SwP, DwP, bcat, bkv, qzero);
  k1_fused<<<NTOT / 32, 512, 0, stream>>>(nodes, mail_data, mem_data, mail_time,
                                          mem_time, time_w, time_b, WcatP, bcat,
                                          nfeat, hb);
  k2_fused<<<RKV / 32, 512, 0, stream>>>(hb, eids, dt_nbr, efeat, time_w, time_b,
                                         WkvP, bkv, KVb);
  kQ_gemm<<<ND_ / 64, 512, 0, stream>>>(hb, WqB, qzero, Qb);
  kAtt<<<ND_ / 4, 256, 0, stream>>>(Qb, KVb, aggb);
  kO_ln<<<ND_ / 64, 512, 0, stream>>>(hb, aggb, WoB, bo, ln_g, ln_b, emb);
  k3_ep<<<B_, 128, 0, stream>>>(emb, SwP, DwP, ep_sb, ep_db, ep_ow, ep_ob, out);
}